// Round 2
// baseline (760.818 us; speedup 1.0000x reference)
//
#include <hip/hip_runtime.h>
#include <math.h>

// Problem constants (fixed by the reference)
#define C_   4096
#define H_   256
#define V_   16000
#define SPW  32
#define NB   32    // N (batch)
#define TT   128   // T (sequence length)
#define NTOK ((TT - 1) * NB)          // 4064 token transitions
#define NITEM (NTOK * SPW)            // 130048 (nt, i) row-uses

// ---------------------------------------------------------------------------
// Workspace layout (float offsets). Total ~27.0M floats = ~108 MB.
// ---------------------------------------------------------------------------
static const size_t OFF_TL    = 0;                                   // C*C transition logits
static const size_t OFF_RES   = OFF_TL   + (size_t)C_ * C_;          // C*H residual out (reused 3x sequentially)
static const size_t OFF_STMP  = OFF_RES  + (size_t)C_ * H_;          // C   start pre-softmax
static const size_t OFF_START = OFF_STMP + C_;                       // C   start log-probs
static const size_t OFF_LSE1  = OFF_START + C_;                      // C
static const size_t OFF_LSE2  = OFF_LSE1 + C_;                       // C
static const size_t OFF_RMAX  = OFF_LSE2 + C_;                       // C (unsigned, encoded-float max)
static const size_t OFF_RSUM  = OFF_RMAX + C_;                       // C
static const size_t OFF_DEN   = OFF_RSUM + C_;                       // C emission row log-denominator
static const size_t OFF_LOGZ  = OFF_DEN  + C_;                       // NB (padded to 64)
static const size_t OFF_ELBO  = OFF_LOGZ + 64;                       // double accumulator
static const size_t OFF_EWT   = OFF_ELBO + 16;                       // V*H transposed e_out_w (dead after em_logits)
static const size_t OFF_L     = OFF_EWT  + (size_t)V_ * H_;          // V*SPW masked emission logits
static const size_t OFF_OBS   = OFF_L    + (size_t)V_ * SPW;         // N*T*SPW
static const size_t OFF_PHI   = OFF_OBS  + (size_t)NB * TT * SPW;    // (T-1)*N*SPW*SPW  phiN[t,n,i,j]  (j inner!)
static const size_t OFF_ALPH  = OFF_PHI  + (size_t)NTOK * SPW * SPW; // (T-1)*N*SPW
static const size_t OFF_BETA  = OFF_ALPH + (size_t)NTOK * SPW;       // (T-1)*N*SPW

// Inverted-index scratch ALIASED onto the dead ewT region (ewT is only live
// transpose_kernel -> em_logits_kernel; index build runs strictly after).
static const size_t OFF_CNT   = OFF_EWT;            // 4096 int
static const size_t OFF_OFFS  = OFF_EWT + 4096;     // 4097 int (pad to 4112)
static const size_t OFF_CUR   = OFF_EWT + 8208;     // 4096 int
static const size_t OFF_ENT   = OFF_EWT + 12304;    // NITEM int

// Monotone float<->uint encoding for atomicMax on floats (handles negatives)
__device__ inline unsigned enc_f(float f) {
    unsigned u = __float_as_uint(f);
    return (u & 0x80000000u) ? ~u : (u | 0x80000000u);
}
__device__ inline float dec_f(unsigned k) {
    return (k & 0x80000000u) ? __uint_as_float(k ^ 0x80000000u) : __uint_as_float(~k);
}

// ---------------------------------------------------------------------------
// K0: init scatter accumulators + elbo accumulator (ws is poisoned each call)
// ---------------------------------------------------------------------------
__global__ void init_kernel(unsigned* __restrict__ rowmax, float* __restrict__ rowsum,
                            double* __restrict__ elbo_acc) {
    int i = blockIdx.x * 256 + threadIdx.x;
    if (i < C_) { rowmax[i] = 0u; rowsum[i] = 0.f; }   // key 0 < key(-inf): safe identity
    if (i == 0) *elbo_acc = 0.0;
}

// ---------------------------------------------------------------------------
// K1: residual MLP  out = relu(relu(x@w1+b1)@w2+b2) + x  over (C,H) rows.
// ---------------------------------------------------------------------------
__global__ __launch_bounds__(256) void residual_kernel(
    const float* __restrict__ x, const float* __restrict__ w1, const float* __restrict__ b1,
    const float* __restrict__ w2, const float* __restrict__ b2, float* __restrict__ out)
{
    __shared__ float xs[16][H_];
    __shared__ float hs[16][H_];
    int t  = threadIdx.x;
    int r0 = blockIdx.x * 16;
    for (int r = 0; r < 16; ++r) xs[r][t] = x[(size_t)(r0 + r) * H_ + t];
    __syncthreads();
    float acc[16];
#pragma unroll
    for (int r = 0; r < 16; ++r) acc[r] = 0.f;
    for (int k = 0; k < H_; ++k) {
        float w = w1[k * H_ + t];
#pragma unroll
        for (int r = 0; r < 16; ++r) acc[r] += xs[r][k] * w;
    }
    float bb = b1[t];
#pragma unroll
    for (int r = 0; r < 16; ++r) hs[r][t] = fmaxf(acc[r] + bb, 0.f);
    __syncthreads();
#pragma unroll
    for (int r = 0; r < 16; ++r) acc[r] = 0.f;
    for (int k = 0; k < H_; ++k) {
        float w = w2[k * H_ + t];
#pragma unroll
        for (int r = 0; r < 16; ++r) acc[r] += hs[r][k] * w;
    }
    float b2v = b2[t];
#pragma unroll
    for (int r = 0; r < 16; ++r)
        out[(size_t)(r0 + r) * H_ + t] = fmaxf(acc[r] + b2v, 0.f) + xs[r][t];
}

// ---------------------------------------------------------------------------
// K2: start head  s[c] = dot(res[c,:], s_out_w) + s_out_b
// ---------------------------------------------------------------------------
__global__ __launch_bounds__(256) void start_head_kernel(
    const float* __restrict__ res, const float* __restrict__ sow,
    const float* __restrict__ sob, float* __restrict__ s_tmp)
{
    int wave = threadIdx.x >> 6;
    int lane = threadIdx.x & 63;
    int c = blockIdx.x * 4 + wave;
    float sum = 0.f;
    for (int k = lane; k < H_; k += 64) sum += res[(size_t)c * H_ + k] * sow[k];
#pragma unroll
    for (int off = 32; off; off >>= 1) sum += __shfl_xor(sum, off);
    if (lane == 0) s_tmp[c] = sum + sob[0];
}

// ---------------------------------------------------------------------------
// K3: log_softmax over C=4096 in one block
// ---------------------------------------------------------------------------
__global__ __launch_bounds__(1024) void logsoftmax_start_kernel(
    const float* __restrict__ s_tmp, float* __restrict__ out)
{
    __shared__ float red_m[16];
    __shared__ float red_s[16];
    int t = threadIdx.x;
    float v[4];
    float m = -INFINITY;
#pragma unroll
    for (int q = 0; q < 4; ++q) { v[q] = s_tmp[t + q * 1024]; m = fmaxf(m, v[q]); }
#pragma unroll
    for (int off = 32; off; off >>= 1) m = fmaxf(m, __shfl_xor(m, off));
    if ((t & 63) == 0) red_m[t >> 6] = m;
    __syncthreads();
    float M = red_m[0];
#pragma unroll
    for (int w = 1; w < 16; ++w) M = fmaxf(M, red_m[w]);
    float s = 0.f;
#pragma unroll
    for (int q = 0; q < 4; ++q) s += expf(v[q] - M);
#pragma unroll
    for (int off = 32; off; off >>= 1) s += __shfl_xor(s, off);
    if ((t & 63) == 0) red_s[t >> 6] = s;
    __syncthreads();
    float S = 0.f;
#pragma unroll
    for (int w = 0; w < 16; ++w) S += red_s[w];
    float lg = logf(S);
#pragma unroll
    for (int q = 0; q < 4; ++q) out[t + q * 1024] = (v[q] - M) - lg;
}

// ---------------------------------------------------------------------------
// K4: TL[i,j] = dot(A[i,:], B[j,:])  — fp32 NT GEMM, 64x64 tile, 4x4/thread
// ---------------------------------------------------------------------------
__global__ __launch_bounds__(256) void matmul_nt_kernel(
    const float* __restrict__ A, const float* __restrict__ B, float* __restrict__ Cmat)
{
    __shared__ __align__(16) float As[16][68];
    __shared__ __align__(16) float Bs[16][68];
    int tid = threadIdx.x;
    int tx = tid & 15, ty = tid >> 4;
    int j0 = blockIdx.x * 64, i0 = blockIdx.y * 64;
    int lrow = tid >> 2;
    int lk   = (tid & 3) * 4;
    const float* Arow = A + (size_t)(i0 + lrow) * H_;
    const float* Brow = B + (size_t)(j0 + lrow) * H_;
    float acc[4][4] = {};
    for (int k0 = 0; k0 < H_; k0 += 16) {
        float4 av = *(const float4*)(Arow + k0 + lk);
        float4 bv = *(const float4*)(Brow + k0 + lk);
        __syncthreads();
        As[lk + 0][lrow] = av.x; As[lk + 1][lrow] = av.y;
        As[lk + 2][lrow] = av.z; As[lk + 3][lrow] = av.w;
        Bs[lk + 0][lrow] = bv.x; Bs[lk + 1][lrow] = bv.y;
        Bs[lk + 2][lrow] = bv.z; Bs[lk + 3][lrow] = bv.w;
        __syncthreads();
#pragma unroll
        for (int kk = 0; kk < 16; ++kk) {
            float4 a4 = *(const float4*)&As[kk][ty * 4];
            float4 b4 = *(const float4*)&Bs[kk][tx * 4];
            float aa[4] = {a4.x, a4.y, a4.z, a4.w};
            float bb[4] = {b4.x, b4.y, b4.z, b4.w};
#pragma unroll
            for (int u = 0; u < 4; ++u)
#pragma unroll
                for (int w = 0; w < 4; ++w) acc[u][w] += aa[u] * bb[w];
        }
    }
#pragma unroll
    for (int u = 0; u < 4; ++u) {
        float4 o = make_float4(acc[u][0], acc[u][1], acc[u][2], acc[u][3]);
        *(float4*)(Cmat + (size_t)(i0 + ty * 4 + u) * C_ + j0 + tx * 4) = o;
    }
}

// ---------------------------------------------------------------------------
// K5: per-row online logsumexp over C columns (optionally minus sub[i])
// ---------------------------------------------------------------------------
__global__ __launch_bounds__(256) void row_lse_kernel(
    const float* __restrict__ TL, const float* __restrict__ sub,
    float* __restrict__ out_lse, int use_sub)
{
    int i = blockIdx.x;
    int t = threadIdx.x;
    float subv = use_sub ? sub[i] : 0.f;
    const float* row = TL + (size_t)i * C_;
    float m = -INFINITY, s = 0.f;
    for (int j = t; j < C_; j += 256) {
        float x = row[j] - subv;
        float nm = fmaxf(m, x);
        s = s * expf(m - nm) + expf(x - nm);
        m = nm;
    }
#pragma unroll
    for (int off = 32; off; off >>= 1) {
        float om = __shfl_xor(m, off);
        float os = __shfl_xor(s, off);
        float nm = fmaxf(m, om);
        s = s * expf(m - nm) + os * expf(om - nm);
        m = nm;
    }
    __shared__ float sm[4], ss[4];
    if ((t & 63) == 0) { sm[t >> 6] = m; ss[t >> 6] = s; }
    __syncthreads();
    if (t == 0) {
        float M = sm[0], S = ss[0];
#pragma unroll
        for (int w = 1; w < 4; ++w) {
            float nm = fmaxf(M, sm[w]);
            S = S * expf(M - nm) + ss[w] * expf(sm[w] - nm);
            M = nm;
        }
        out_lse[i] = M + logf(S);
    }
}

// ---------------------------------------------------------------------------
// K6: transpose e_out_w (H,V) -> ewT (V,H)
// ---------------------------------------------------------------------------
__global__ __launch_bounds__(256) void transpose_kernel(
    const float* __restrict__ W, float* __restrict__ WT)
{
    __shared__ float tile[32][33];
    int tx = threadIdx.x & 31, ty = threadIdx.x >> 5;
    int v0 = blockIdx.x * 32, h0 = blockIdx.y * 32;
#pragma unroll
    for (int q = 0; q < 4; ++q)
        tile[ty + 8 * q][tx] = W[(size_t)(h0 + ty + 8 * q) * V_ + v0 + tx];
    __syncthreads();
#pragma unroll
    for (int q = 0; q < 4; ++q)
        WT[(size_t)(v0 + ty + 8 * q) * H_ + h0 + tx] = tile[tx][ty + 8 * q];
}

// ---------------------------------------------------------------------------
// K7: masked emission logits  L[v,k] = dot(res_pre[w2s[v,k],:], ewT[v,:]) + eob[v]
// ---------------------------------------------------------------------------
__global__ __launch_bounds__(256) void em_logits_kernel(
    const float* __restrict__ res_pre, const float* __restrict__ ewT,
    const float* __restrict__ eob, const int* __restrict__ w2s, float* __restrict__ L)
{
    int v = blockIdx.x;
    __shared__ float wv[H_];
    wv[threadIdx.x] = ewT[(size_t)v * H_ + threadIdx.x];
    __syncthreads();
    int g = threadIdx.x >> 3;
    int l = threadIdx.x & 7;
    int c = w2s[v * SPW + g];
    const float* row = res_pre + (size_t)c * H_;
    float sum = 0.f;
#pragma unroll
    for (int m = 0; m < 32; ++m) { int idx = l + m * 8; sum += row[idx] * wv[idx]; }
    sum += __shfl_xor(sum, 1);
    sum += __shfl_xor(sum, 2);
    sum += __shfl_xor(sum, 4);
    if (l == 0) L[v * SPW + g] = sum + eob[v];
}

// ---------------------------------------------------------------------------
// K8/K9: scatter per-state max, then sum(exp(x-max)), deduping repeated states
// ---------------------------------------------------------------------------
__global__ __launch_bounds__(256) void row_max_kernel(
    const int* __restrict__ w2s, const float* __restrict__ L, unsigned* __restrict__ rowmax)
{
    __shared__ int st[8][32];
    int vl = threadIdx.x >> 5, k = threadIdx.x & 31;
    int v = blockIdx.x * 8 + vl;
    st[vl][k] = w2s[v * SPW + k];
    __syncthreads();
    int c = st[vl][k];
    bool dup = false;
    for (int kp = 0; kp < k; ++kp) if (st[vl][kp] == c) { dup = true; break; }
    if (!dup) atomicMax(&rowmax[c], enc_f(L[v * SPW + k]));
}

__global__ __launch_bounds__(256) void row_sum_kernel(
    const int* __restrict__ w2s, const float* __restrict__ L,
    const unsigned* __restrict__ rowmax, float* __restrict__ rowsum)
{
    __shared__ int st[8][32];
    int vl = threadIdx.x >> 5, k = threadIdx.x & 31;
    int v = blockIdx.x * 8 + vl;
    st[vl][k] = w2s[v * SPW + k];
    __syncthreads();
    int c = st[vl][k];
    bool dup = false;
    for (int kp = 0; kp < k; ++kp) if (st[vl][kp] == c) { dup = true; break; }
    if (!dup) atomicAdd(&rowsum[c], expf(L[v * SPW + k] - dec_f(rowmax[c])));
}

__global__ void denom_kernel(const unsigned* __restrict__ rowmax,
                             const float* __restrict__ rowsum, float* __restrict__ denom)
{
    int c = blockIdx.x * 256 + threadIdx.x;
    if (c >= C_) return;
    unsigned k = rowmax[c];
    denom[c] = (k == 0u) ? -INFINITY : (dec_f(k) + logf(rowsum[c]));
}

// ---------------------------------------------------------------------------
// K11: obs[n,t,k] = L[text[n,t],k] - denom[w2s[text[n,t],k]]
// ---------------------------------------------------------------------------
__global__ void obs_kernel(const int* __restrict__ text, const int* __restrict__ w2s,
                           const float* __restrict__ L, const float* __restrict__ denom,
                           float* __restrict__ obs)
{
    int idx = blockIdx.x * 256 + threadIdx.x;
    if (idx >= NB * TT * SPW) return;
    int k = idx & 31;
    int nt = idx >> 5;
    int v = text[nt];
    int c = w2s[v * SPW + k];
    obs[idx] = L[v * SPW + k] - denom[c];
}

// ---------------------------------------------------------------------------
// Inverted index build: for each of the NITEM (nt,i) row-uses, bucket by
// ci = w2s[text[n,t], i].  (aliased onto dead ewT region)
// ---------------------------------------------------------------------------
__global__ void zero_count_kernel(int* __restrict__ count) {
    int i = blockIdx.x * 256 + threadIdx.x;
    if (i < C_) count[i] = 0;
}

__global__ void hist_kernel(const int* __restrict__ text, const int* __restrict__ w2s,
                            int* __restrict__ count) {
    int item = blockIdx.x * 256 + threadIdx.x;   // < NITEM
    int i  = item & 31;
    int nt = item >> 5;
    int t = nt >> 5, n = nt & 31;
    int v0 = text[n * TT + t];
    int ci = w2s[v0 * SPW + i];
    atomicAdd(&count[ci], 1);
}

__global__ __launch_bounds__(1024) void prefix_kernel(const int* __restrict__ count,
                                                      int* __restrict__ offs,
                                                      int* __restrict__ cursor) {
    __shared__ int buf[1024];
    int t = threadIdx.x;
    int c0 = count[t * 4 + 0], c1 = count[t * 4 + 1];
    int c2 = count[t * 4 + 2], c3 = count[t * 4 + 3];
    int s = c0 + c1 + c2 + c3;
    buf[t] = s;
    __syncthreads();
    for (int d = 1; d < 1024; d <<= 1) {
        int v = (t >= d) ? buf[t - d] : 0;
        __syncthreads();
        buf[t] += v;
        __syncthreads();
    }
    int excl = buf[t] - s;
    offs[t * 4 + 0] = excl; cursor[t * 4 + 0] = excl; excl += c0;
    offs[t * 4 + 1] = excl; cursor[t * 4 + 1] = excl; excl += c1;
    offs[t * 4 + 2] = excl; cursor[t * 4 + 2] = excl; excl += c2;
    offs[t * 4 + 3] = excl; cursor[t * 4 + 3] = excl;
    if (t == 1023) offs[4096] = buf[1023];
}

__global__ void fill_kernel(const int* __restrict__ text, const int* __restrict__ w2s,
                            int* __restrict__ cursor, int* __restrict__ entries) {
    int item = blockIdx.x * 256 + threadIdx.x;
    int i  = item & 31;
    int nt = item >> 5;
    int t = nt >> 5, n = nt & 31;
    int v0 = text[n * TT + t];
    int ci = w2s[v0 * SPW + i];
    int pos = atomicAdd(&cursor[ci], 1);
    entries[pos] = item;
}

// ---------------------------------------------------------------------------
// K12: phi gather, inverted.  One block per TL row ci: stage the 16 KB row
// in LDS (coalesced, TL read exactly once), then serve each (nt,i) use with
// coalesced w2s/obs reads, LDS gathers, and a coalesced 128 B phi write.
// phiN layout: [t, n, i, j]  (j innermost).
// ---------------------------------------------------------------------------
__global__ __launch_bounds__(256) void phi_gather_kernel(
    const float* __restrict__ TL, const int* __restrict__ offs, const int* __restrict__ entries,
    const float* __restrict__ lse1, const float* __restrict__ lse2,
    const float* __restrict__ start_log, const float* __restrict__ obs,
    const int* __restrict__ text, const int* __restrict__ w2s, float* __restrict__ phiN)
{
    int ci = blockIdx.x;
    __shared__ float row[C_];   // 16 KB
    {
        const float4* src = (const float4*)(TL + (size_t)ci * C_);
        float4* dst = (float4*)row;
        for (int q = threadIdx.x; q < C_ / 4; q += 256) dst[q] = src[q];
    }
    __syncthreads();
    float abase = -lse1[ci] - lse2[ci];
    float st = start_log[ci];
    int beg = offs[ci], end = offs[ci + 1];
    int g = threadIdx.x >> 5, lane = threadIdx.x & 31;
    for (int idx = beg + g; idx < end; idx += 8) {
        int item = entries[idx];
        int i  = item & 31;
        int nt = item >> 5;
        int t = nt >> 5, n = nt & 31;
        int v1 = text[n * TT + t + 1];
        int cj = w2s[v1 * SPW + lane];
        float ob = obs[(size_t)(n * TT + t + 1) * SPW + lane];
        float a = abase;
        if (t == 0) a += st + obs[(size_t)(n * TT) * SPW + i];
        phiN[(size_t)nt * 1024 + i * 32 + lane] = row[cj] + a + ob;
    }
}

// ---------------------------------------------------------------------------
// K13: forward + backward scans (blocks 0..31 fwd, 32..63 bwd, concurrent).
// phiN layout [t,n,i,j]: fwd reduces over i (strided read, L1-served),
// bwd reduces over j (coalesced read).
// ---------------------------------------------------------------------------
__global__ __launch_bounds__(1024) void scan_kernel(
    const float* __restrict__ phiN, float* __restrict__ alphas_pre,
    float* __restrict__ betas_next, float* __restrict__ logZ, float* __restrict__ out)
{
    bool bwd = blockIdx.x >= NB;
    int n = blockIdx.x & (NB - 1);
    int tid = threadIdx.x;
    int a = tid >> 5, r = tid & 31;
    __shared__ float carry[32];
    if (tid < 32) carry[tid] = 0.f;
    __syncthreads();

    if (!bwd) {
        // new[j=a] = lse over i=r of carry[i] + phi[i][j]
        float pnext = phiN[(size_t)(0 * NB + n) * 1024 + r * 32 + a];
        for (int t = 0; t < TT - 1; ++t) {
            float cr = carry[r];
            float cold = (tid < 32) ? carry[tid] : 0.f;
            float p = pnext + cr;
            if (t + 1 < TT - 1)
                pnext = phiN[(size_t)((t + 1) * NB + n) * 1024 + r * 32 + a];
            float m = p;
#pragma unroll
            for (int off = 16; off; off >>= 1) m = fmaxf(m, __shfl_xor(m, off));
            float s = expf(p - m);
#pragma unroll
            for (int off = 16; off; off >>= 1) s += __shfl_xor(s, off);
            float nv = m + logf(s);
            if (tid < 32) alphas_pre[((size_t)t * NB + n) * SPW + tid] = cold;
            __syncthreads();
            if (r == 0) carry[a] = nv;
            __syncthreads();
        }
        if (tid < 32) {
            float x = carry[tid];
            float m = x;
#pragma unroll
            for (int off = 16; off; off >>= 1) m = fmaxf(m, __shfl_xor(m, off));
            float s = expf(x - m);
#pragma unroll
            for (int off = 16; off; off >>= 1) s += __shfl_xor(s, off);
            float lg = logf(s);
            if (tid == 0) logZ[n] = m + lg;
            out[2 + n * 32 + tid] = (x - m) - lg;
        }
    } else {
        // new[i=a] = lse over j=r of phi[i][j] + carry[j]
        float pnext = phiN[(size_t)((TT - 2) * NB + n) * 1024 + a * 32 + r];
        for (int t = TT - 2; t >= 0; --t) {
            float cr = carry[r];
            float cold = (tid < 32) ? carry[tid] : 0.f;
            float p = pnext + cr;
            if (t > 0)
                pnext = phiN[(size_t)((t - 1) * NB + n) * 1024 + a * 32 + r];
            float m = p;
#pragma unroll
            for (int off = 16; off; off >>= 1) m = fmaxf(m, __shfl_xor(m, off));
            float s = expf(p - m);
#pragma unroll
            for (int off = 16; off; off >>= 1) s += __shfl_xor(s, off);
            float nv = m + logf(s);
            if (tid < 32) betas_next[((size_t)t * NB + n) * SPW + tid] = cold;
            __syncthreads();
            if (r == 0) carry[a] = nv;
            __syncthreads();
        }
    }
}

// ---------------------------------------------------------------------------
// K14: elbo — phiN layout [t,n,i,j]: lm = ap[i] + phi + bn[j] - logZ
// ---------------------------------------------------------------------------
__global__ __launch_bounds__(256) void elbo_kernel(
    const float* __restrict__ phiN, const float* __restrict__ alphas_pre,
    const float* __restrict__ betas_next, const float* __restrict__ logZ,
    double* __restrict__ elbo_acc)
{
    int t = blockIdx.x / NB;
    int n = blockIdx.x - t * NB;
    int tid = threadIdx.x;
    __shared__ float ap[32], bn[32];
    if (tid < 32) ap[tid] = alphas_pre[((size_t)t * NB + n) * SPW + tid];
    else if (tid < 64) bn[tid - 32] = betas_next[((size_t)t * NB + n) * SPW + (tid - 32)];
    __syncthreads();
    float lz = logZ[n];
    size_t base = (size_t)(t * NB + n) * 1024;
    double local = 0.0;
#pragma unroll
    for (int e = tid; e < 1024; e += 256) {
        int i = e >> 5, j = e & 31;
        float ph = phiN[base + e];
        float lm = ap[i] + ph + bn[j] - lz;
        local += (double)(expf(lm) * ph);
    }
#pragma unroll
    for (int off = 32; off; off >>= 1) local += __shfl_down(local, off);
    __shared__ double wsum[4];
    if ((tid & 63) == 0) wsum[tid >> 6] = local;
    __syncthreads();
    if (tid == 0) atomicAdd(elbo_acc, wsum[0] + wsum[1] + wsum[2] + wsum[3]);
}

// K15: finalize scalar outputs
__global__ void finalize_kernel(const double* __restrict__ elbo_acc,
                                const float* __restrict__ logZ, float* __restrict__ out)
{
    if (threadIdx.x == 0) {
        out[0] = (float)(*elbo_acc);
        float s = 0.f;
        for (int n = 0; n < NB; ++n) s += logZ[n];
        out[1] = s;
    }
}

// ---------------------------------------------------------------------------
extern "C" void kernel_launch(void* const* d_in, const int* in_sizes, int n_in,
                              void* d_out, int out_size, void* d_ws, size_t ws_size,
                              hipStream_t stream) {
    (void)in_sizes; (void)n_in; (void)out_size; (void)ws_size;
    const float* start_emb = (const float*)d_in[0];
    const float* sw1  = (const float*)d_in[1];
    const float* sb1  = (const float*)d_in[2];
    const float* sw2  = (const float*)d_in[3];
    const float* sb2  = (const float*)d_in[4];
    const float* sow  = (const float*)d_in[5];
    const float* sob  = (const float*)d_in[6];
    const float* state_emb = (const float*)d_in[7];
    const float* tw1  = (const float*)d_in[8];
    const float* tb1  = (const float*)d_in[9];
    const float* tw2  = (const float*)d_in[10];
    const float* tb2  = (const float*)d_in[11];
    const float* nsp  = (const float*)d_in[12];
    const float* pre_emb = (const float*)d_in[13];
    const float* ew1  = (const float*)d_in[14];
    const float* eb1  = (const float*)d_in[15];
    const float* ew2  = (const float*)d_in[16];
    const float* eb2  = (const float*)d_in[17];
    const float* eow  = (const float*)d_in[18];
    const float* eob  = (const float*)d_in[19];
    const int*   text = (const int*)d_in[20];
    const int*   w2s  = (const int*)d_in[21];

    float* ws = (float*)d_ws;
    float* TL      = ws + OFF_TL;
    float* res     = ws + OFF_RES;
    float* s_tmp   = ws + OFF_STMP;
    float* startl  = ws + OFF_START;
    float* lse1    = ws + OFF_LSE1;
    float* lse2    = ws + OFF_LSE2;
    unsigned* rmax = (unsigned*)(ws + OFF_RMAX);
    float* rsum    = ws + OFF_RSUM;
    float* den     = ws + OFF_DEN;
    float* logZ    = ws + OFF_LOGZ;
    double* elboA  = (double*)(ws + OFF_ELBO);
    float* ewT     = ws + OFF_EWT;
    float* Lm      = ws + OFF_L;
    float* obs     = ws + OFF_OBS;
    float* phiN    = ws + OFF_PHI;
    float* alph    = ws + OFF_ALPH;
    float* beta    = ws + OFF_BETA;
    int* cnt       = (int*)(ws + OFF_CNT);
    int* offs      = (int*)(ws + OFF_OFFS);
    int* cur       = (int*)(ws + OFF_CUR);
    int* ent       = (int*)(ws + OFF_ENT);
    float* out     = (float*)d_out;

    init_kernel<<<16, 256, 0, stream>>>(rmax, rsum, elboA);

    // start path
    residual_kernel<<<C_ / 16, 256, 0, stream>>>(start_emb, sw1, sb1, sw2, sb2, res);
    start_head_kernel<<<C_ / 4, 256, 0, stream>>>(res, sow, sob, s_tmp);
    logsoftmax_start_kernel<<<1, 1024, 0, stream>>>(s_tmp, startl);

    // transition path
    residual_kernel<<<C_ / 16, 256, 0, stream>>>(state_emb, tw1, tb1, tw2, tb2, res);
    matmul_nt_kernel<<<dim3(64, 64), 256, 0, stream>>>(res, nsp, TL);
    row_lse_kernel<<<C_, 256, 0, stream>>>(TL, nullptr, lse1, 0);
    row_lse_kernel<<<C_, 256, 0, stream>>>(TL, lse1, lse2, 1);

    // emission path (sparse: only the V*SPW masked entries)
    residual_kernel<<<C_ / 16, 256, 0, stream>>>(pre_emb, ew1, eb1, ew2, eb2, res);
    transpose_kernel<<<dim3(V_ / 32, H_ / 32), 256, 0, stream>>>(eow, ewT);
    em_logits_kernel<<<V_, 256, 0, stream>>>(res, ewT, eob, w2s, Lm);
    row_max_kernel<<<V_ / 8, 256, 0, stream>>>(w2s, Lm, rmax);
    row_sum_kernel<<<V_ / 8, 256, 0, stream>>>(w2s, Lm, rmax, rsum);
    denom_kernel<<<16, 256, 0, stream>>>(rmax, rsum, den);
    obs_kernel<<<(NB * TT * SPW) / 256, 256, 0, stream>>>(text, w2s, Lm, den, obs);

    // inverted index (aliased onto dead ewT region — must run after em_logits)
    zero_count_kernel<<<16, 256, 0, stream>>>(cnt);
    hist_kernel<<<NITEM / 256, 256, 0, stream>>>(text, w2s, cnt);
    prefix_kernel<<<1, 1024, 0, stream>>>(cnt, offs, cur);
    fill_kernel<<<NITEM / 256, 256, 0, stream>>>(text, w2s, cur, ent);

    // phi assembly (coalesced, TL read once) + scans + outputs
    phi_gather_kernel<<<C_, 256, 0, stream>>>(TL, offs, ent, lse1, lse2, startl,
                                              obs, text, w2s, phiN);
    scan_kernel<<<2 * NB, 1024, 0, stream>>>(phiN, alph, beta, logZ, out);
    elbo_kernel<<<(TT - 1) * NB, 256, 0, stream>>>(phiN, alph, beta, logZ, elboA);
    finalize_kernel<<<1, 64, 0, stream>>>(elboA, logZ, out);
}

// Round 3
// 716.508 us; speedup vs baseline: 1.0618x; 1.0618x over previous
//
#include <hip/hip_runtime.h>
#include <hip/hip_fp16.h>
#include <math.h>

// Problem constants (fixed by the reference)
#define C_   4096
#define H_   256
#define V_   16000
#define SPW  32
#define NB   32    // N (batch)
#define TT   128   // T (sequence length)
#define NTOK ((TT - 1) * NB)          // 4064 token transitions
#define NITEM (NTOK * SPW)            // 130048 (nt, i) row-uses
#define GEMM_K 768                    // 3 x 256 split-fp16 segments

// ---------------------------------------------------------------------------
// Workspace layout (float offsets). Total ~27.0M floats = ~108 MB.
// ---------------------------------------------------------------------------
static const size_t OFF_TL    = 0;                                   // C*C transition logits
static const size_t OFF_RES   = OFF_TL   + (size_t)C_ * C_;          // C*H residual out (transition)
static const size_t OFF_STMP  = OFF_RES  + (size_t)C_ * H_;          // C   start pre-softmax
static const size_t OFF_START = OFF_STMP + C_;                       // C   start log-probs
static const size_t OFF_LSE1  = OFF_START + C_;                      // C
static const size_t OFF_LSE2  = OFF_LSE1 + C_;                       // C (unused, kept for layout)
static const size_t OFF_RMAX  = OFF_LSE2 + C_;                       // C (unsigned, encoded-float max)
static const size_t OFF_RSUM  = OFF_RMAX + C_;                       // C
static const size_t OFF_DEN   = OFF_RSUM + C_;                       // C emission row log-denominator
static const size_t OFF_LOGZ  = OFF_DEN  + C_;                       // NB (padded to 64)
static const size_t OFF_ELBO  = OFF_LOGZ + 64;                       // double accumulator
static const size_t OFF_EWT   = OFF_ELBO + 16;                       // V*H region (A'/B' early, ewT later)
static const size_t OFF_L     = OFF_EWT  + (size_t)V_ * H_;          // V*SPW masked emission logits
static const size_t OFF_OBS   = OFF_L    + (size_t)V_ * SPW;         // N*T*SPW
static const size_t OFF_PHI   = OFF_OBS  + (size_t)NB * TT * SPW;    // (T-1)*N*SPW*SPW  phiN[t,n,i,j]
static const size_t OFF_ALPH  = OFF_PHI  + (size_t)NTOK * SPW * SPW; // (T-1)*N*SPW
static const size_t OFF_BETA  = OFF_ALPH + (size_t)NTOK * SPW;       // (T-1)*N*SPW

// A'/B' packed split-fp16 GEMM operands: aliased onto ewT region.
// Lifetime: convert -> gemm. ewT itself is live transpose -> em_logits (later).
static const size_t OFF_AP    = OFF_EWT;                              // C*768 ushort = 1.5M floats
static const size_t OFF_BP    = OFF_EWT + (size_t)C_ * GEMM_K / 2;    // C*768 ushort

// res_s / res_e aliased onto phi region (phi written much later by phi_gather).
static const size_t OFF_RES_S = OFF_PHI;
static const size_t OFF_RES_E = OFF_PHI + (size_t)C_ * H_;

// Inverted-index scratch aliased onto alpha/beta region (alphas/betas are
// written by scan_kernel, which runs strictly after phi_gather consumed it).
static const size_t OFF_CNT   = OFF_ALPH;            // 4096 int
static const size_t OFF_OFFS  = OFF_ALPH + 4096;     // 4097 int (pad to 4112)
static const size_t OFF_CUR   = OFF_ALPH + 8208;     // 4096 int
static const size_t OFF_ENT   = OFF_ALPH + 12304;    // NITEM int

// Monotone float<->uint encoding for atomicMax on floats (handles negatives)
__device__ inline unsigned enc_f(float f) {
    unsigned u = __float_as_uint(f);
    return (u & 0x80000000u) ? ~u : (u | 0x80000000u);
}
__device__ inline float dec_f(unsigned k) {
    return (k & 0x80000000u) ? __uint_as_float(k ^ 0x80000000u) : __uint_as_float(~k);
}

typedef __attribute__((ext_vector_type(8))) short short8;
typedef __attribute__((ext_vector_type(4))) float floatx4;

#define GLB(p)  ((const __attribute__((address_space(1))) unsigned int*)(p))
#define LDSP(p) ((__attribute__((address_space(3))) unsigned int*)(p))

// ---------------------------------------------------------------------------
// K0: init accumulators + index counters (ws is poisoned each call)
// ---------------------------------------------------------------------------
__global__ void init_kernel(unsigned* __restrict__ rowmax, float* __restrict__ rowsum,
                            int* __restrict__ cnt, double* __restrict__ elbo_acc) {
    int i = blockIdx.x * 256 + threadIdx.x;
    if (i < C_) { rowmax[i] = 0u; rowsum[i] = 0.f; cnt[i] = 0; }
    if (i == 0) *elbo_acc = 0.0;
}

// ---------------------------------------------------------------------------
// K1: three residual MLPs in ONE launch (blockIdx.x>>8 selects instance).
// out = relu(relu(x@w1+b1)@w2+b2) + x over (C,H) rows, 16 rows/block.
// ---------------------------------------------------------------------------
struct ResArgs {
    const float *x, *w1, *b1, *w2, *b2;
    float* out;
};

__global__ __launch_bounds__(256) void residual3_kernel(ResArgs a0, ResArgs a1, ResArgs a2)
{
    ResArgs a = (blockIdx.x < 256) ? a0 : (blockIdx.x < 512 ? a1 : a2);
    int blk = blockIdx.x & 255;
    __shared__ float xs[16][H_];
    __shared__ float hs[16][H_];
    int t  = threadIdx.x;
    int r0 = blk * 16;
    for (int r = 0; r < 16; ++r) xs[r][t] = a.x[(size_t)(r0 + r) * H_ + t];
    __syncthreads();
    float acc[16];
#pragma unroll
    for (int r = 0; r < 16; ++r) acc[r] = 0.f;
    for (int k = 0; k < H_; ++k) {
        float w = a.w1[k * H_ + t];
#pragma unroll
        for (int r = 0; r < 16; ++r) acc[r] += xs[r][k] * w;
    }
    float bb = a.b1[t];
#pragma unroll
    for (int r = 0; r < 16; ++r) hs[r][t] = fmaxf(acc[r] + bb, 0.f);
    __syncthreads();
#pragma unroll
    for (int r = 0; r < 16; ++r) acc[r] = 0.f;
    for (int k = 0; k < H_; ++k) {
        float w = a.w2[k * H_ + t];
#pragma unroll
        for (int r = 0; r < 16; ++r) acc[r] += hs[r][k] * w;
    }
    float b2v = a.b2[t];
#pragma unroll
    for (int r = 0; r < 16; ++r)
        a.out[(size_t)(r0 + r) * H_ + t] = fmaxf(acc[r] + b2v, 0.f) + xs[r][t];
}

// ---------------------------------------------------------------------------
// K2: start head  s[c] = dot(res[c,:], s_out_w) + s_out_b
// ---------------------------------------------------------------------------
__global__ __launch_bounds__(256) void start_head_kernel(
    const float* __restrict__ res, const float* __restrict__ sow,
    const float* __restrict__ sob, float* __restrict__ s_tmp)
{
    int wave = threadIdx.x >> 6;
    int lane = threadIdx.x & 63;
    int c = blockIdx.x * 4 + wave;
    float sum = 0.f;
    for (int k = lane; k < H_; k += 64) sum += res[(size_t)c * H_ + k] * sow[k];
#pragma unroll
    for (int off = 32; off; off >>= 1) sum += __shfl_xor(sum, off);
    if (lane == 0) s_tmp[c] = sum + sob[0];
}

// ---------------------------------------------------------------------------
// K3: log_softmax over C=4096 in one block
// ---------------------------------------------------------------------------
__global__ __launch_bounds__(1024) void logsoftmax_start_kernel(
    const float* __restrict__ s_tmp, float* __restrict__ out)
{
    __shared__ float red_m[16];
    __shared__ float red_s[16];
    int t = threadIdx.x;
    float v[4];
    float m = -INFINITY;
#pragma unroll
    for (int q = 0; q < 4; ++q) { v[q] = s_tmp[t + q * 1024]; m = fmaxf(m, v[q]); }
#pragma unroll
    for (int off = 32; off; off >>= 1) m = fmaxf(m, __shfl_xor(m, off));
    if ((t & 63) == 0) red_m[t >> 6] = m;
    __syncthreads();
    float M = red_m[0];
#pragma unroll
    for (int w = 1; w < 16; ++w) M = fmaxf(M, red_m[w]);
    float s = 0.f;
#pragma unroll
    for (int q = 0; q < 4; ++q) s += expf(v[q] - M);
#pragma unroll
    for (int off = 32; off; off >>= 1) s += __shfl_xor(s, off);
    if ((t & 63) == 0) red_s[t >> 6] = s;
    __syncthreads();
    float S = 0.f;
#pragma unroll
    for (int w = 0; w < 16; ++w) S += red_s[w];
    float lg = logf(S);
#pragma unroll
    for (int q = 0; q < 4; ++q) out[t + q * 1024] = (v[q] - M) - lg;
}

// ---------------------------------------------------------------------------
// K4a: split fp32 -> (f16 hi, f16 lo) and pack GEMM operands:
//   A' = [A1 | A2 | A1]  (C x 768),  B' = [B1 | B1 | B2]  (C x 768)
// so  A'.B'^T = A1B1 + A2B1 + A1B2  ~= A.B^T  (error ~2^-22 relative).
// ---------------------------------------------------------------------------
__global__ void convert_kernel(const float* __restrict__ A, const float* __restrict__ B,
                               unsigned short* __restrict__ Ap, unsigned short* __restrict__ Bp)
{
    int t = blockIdx.x * 256 + threadIdx.x;   // over 2 * C*H/4 float4s
    const int QH = C_ * H_ / 4;
    bool isB = t >= QH;
    int e4 = isB ? t - QH : t;
    const float4* src = (const float4*)(isB ? B : A);
    unsigned short* dst = isB ? Bp : Ap;
    float4 v = src[e4];
    int r = e4 >> 6;            // H_/4 = 64 float4s per row
    int c = (e4 & 63) * 4;
    float vv[4] = {v.x, v.y, v.z, v.w};
    union { unsigned short s[4]; ushort4 u; } hi, lo;
#pragma unroll
    for (int q = 0; q < 4; ++q) {
        __half h = __float2half(vv[q]);
        float hf = __half2float(h);
        __half l = __float2half(vv[q] - hf);
        __builtin_memcpy(&hi.s[q], &h, 2);
        __builtin_memcpy(&lo.s[q], &l, 2);
    }
    size_t base = (size_t)r * GEMM_K + c;
    if (!isB) {
        *(ushort4*)&dst[base]       = hi.u;
        *(ushort4*)&dst[base + 256] = lo.u;
        *(ushort4*)&dst[base + 512] = hi.u;
    } else {
        *(ushort4*)&dst[base]       = hi.u;
        *(ushort4*)&dst[base + 256] = hi.u;
        *(ushort4*)&dst[base + 512] = lo.u;
    }
}

// ---------------------------------------------------------------------------
// K4b: TL = A'.B'^T  f16 MFMA NT-GEMM, K=768. 128x128 tile, 4 waves, each
// wave 64x64 (4x4 fragments of 16x16x32). global_load_lds width=16 staging.
// ---------------------------------------------------------------------------
__global__ __launch_bounds__(256) void gemm_bt_kernel(
    const unsigned short* __restrict__ Ap, const unsigned short* __restrict__ Bp,
    float* __restrict__ Cmat)
{
    __shared__ __align__(16) unsigned short As[128 * 64];   // [row][k], 16 KB
    __shared__ __align__(16) unsigned short Bs[128 * 64];
    int tid = threadIdx.x;
    int i0 = blockIdx.y * 128, j0 = blockIdx.x * 128;
    int wave = tid >> 6, lane = tid & 63;
    int wm = (wave & 1) * 64, wn = (wave >> 1) * 64;
    int l15 = lane & 15, quad = lane >> 4;

    floatx4 acc[4][4] = {};

    int c0row = tid >> 3;            // 0..31
    int c0col = (tid & 7) * 8;       // 0,8,..,56

    for (int k0 = 0; k0 < GEMM_K; k0 += 64) {
        __syncthreads();
#pragma unroll
        for (int q = 0; q < 4; ++q) {
            int row = c0row + q * 32;
            const unsigned short* ga = Ap + (size_t)(i0 + row) * GEMM_K + k0 + c0col;
            const unsigned short* gb = Bp + (size_t)(j0 + row) * GEMM_K + k0 + c0col;
            __builtin_amdgcn_global_load_lds(GLB(ga), LDSP(&As[(size_t)row * 64 + c0col]), 16, 0, 0);
            __builtin_amdgcn_global_load_lds(GLB(gb), LDSP(&Bs[(size_t)row * 64 + c0col]), 16, 0, 0);
        }
        __syncthreads();
#pragma unroll
        for (int ks = 0; ks < 64; ks += 32) {
            short8 af[4], bfr[4];
#pragma unroll
            for (int mi = 0; mi < 4; ++mi)
                af[mi] = *(const short8*)&As[(wm + mi * 16 + l15) * 64 + ks + quad * 8];
#pragma unroll
            for (int ni = 0; ni < 4; ++ni)
                bfr[ni] = *(const short8*)&Bs[(wn + ni * 16 + l15) * 64 + ks + quad * 8];
#pragma unroll
            for (int mi = 0; mi < 4; ++mi)
#pragma unroll
                for (int ni = 0; ni < 4; ++ni)
                    acc[mi][ni] = __builtin_amdgcn_mfma_f32_16x16x32_f16(
                        af[mi], bfr[ni], acc[mi][ni], 0, 0, 0);
        }
    }
    // C/D layout: col = lane&15, row = quad*4 + reg  [m89-verified]
#pragma unroll
    for (int mi = 0; mi < 4; ++mi) {
#pragma unroll
        for (int reg = 0; reg < 4; ++reg) {
            int row = i0 + wm + mi * 16 + quad * 4 + reg;
            float* crow = Cmat + (size_t)row * C_ + j0 + wn;
#pragma unroll
            for (int ni = 0; ni < 4; ++ni)
                crow[ni * 16 + l15] = acc[mi][ni][reg];
        }
    }
}

// ---------------------------------------------------------------------------
// K5: per-row online logsumexp over C columns (single pass; the reference's
// second log_softmax is mathematically identity, numerically ~1e-6 -> dropped)
// ---------------------------------------------------------------------------
__global__ __launch_bounds__(256) void row_lse_kernel(
    const float* __restrict__ TL, float* __restrict__ out_lse)
{
    int i = blockIdx.x;
    int t = threadIdx.x;
    const float* row = TL + (size_t)i * C_;
    float m = -INFINITY, s = 0.f;
    for (int j = t; j < C_; j += 256) {
        float x = row[j];
        float nm = fmaxf(m, x);
        s = s * expf(m - nm) + expf(x - nm);
        m = nm;
    }
#pragma unroll
    for (int off = 32; off; off >>= 1) {
        float om = __shfl_xor(m, off);
        float os = __shfl_xor(s, off);
        float nm = fmaxf(m, om);
        s = s * expf(m - nm) + os * expf(om - nm);
        m = nm;
    }
    __shared__ float sm[4], ss[4];
    if ((t & 63) == 0) { sm[t >> 6] = m; ss[t >> 6] = s; }
    __syncthreads();
    if (t == 0) {
        float M = sm[0], S = ss[0];
#pragma unroll
        for (int w = 1; w < 4; ++w) {
            float nm = fmaxf(M, sm[w]);
            S = S * expf(M - nm) + ss[w] * expf(sm[w] - nm);
            M = nm;
        }
        out_lse[i] = M + logf(S);
    }
}

// ---------------------------------------------------------------------------
// K6: transpose e_out_w (H,V) -> ewT (V,H)
// ---------------------------------------------------------------------------
__global__ __launch_bounds__(256) void transpose_kernel(
    const float* __restrict__ W, float* __restrict__ WT)
{
    __shared__ float tile[32][33];
    int tx = threadIdx.x & 31, ty = threadIdx.x >> 5;
    int v0 = blockIdx.x * 32, h0 = blockIdx.y * 32;
#pragma unroll
    for (int q = 0; q < 4; ++q)
        tile[ty + 8 * q][tx] = W[(size_t)(h0 + ty + 8 * q) * V_ + v0 + tx];
    __syncthreads();
#pragma unroll
    for (int q = 0; q < 4; ++q)
        WT[(size_t)(v0 + ty + 8 * q) * H_ + h0 + tx] = tile[tx][ty + 8 * q];
}

// ---------------------------------------------------------------------------
// K7: masked emission logits, float4 dots (8 lanes x float4 per (v,k))
// ---------------------------------------------------------------------------
__global__ __launch_bounds__(256) void em_logits_kernel(
    const float* __restrict__ res_pre, const float* __restrict__ ewT,
    const float* __restrict__ eob, const int* __restrict__ w2s, float* __restrict__ L)
{
    int v = blockIdx.x;
    __shared__ __align__(16) float wv[H_];
    wv[threadIdx.x] = ewT[(size_t)v * H_ + threadIdx.x];
    __syncthreads();
    int g = threadIdx.x >> 3;
    int l = threadIdx.x & 7;
    int c = w2s[v * SPW + g];
    const float4* row4 = (const float4*)(res_pre + (size_t)c * H_);
    const float4* wv4 = (const float4*)wv;
    float sum = 0.f;
#pragma unroll
    for (int m = 0; m < 8; ++m) {
        float4 r = row4[l + m * 8];
        float4 w = wv4[l + m * 8];
        sum += r.x * w.x + r.y * w.y + r.z * w.z + r.w * w.w;
    }
    sum += __shfl_xor(sum, 1);
    sum += __shfl_xor(sum, 2);
    sum += __shfl_xor(sum, 4);
    if (l == 0) L[v * SPW + g] = sum + eob[v];
}

// ---------------------------------------------------------------------------
// K8/K9: scatter per-state max, then sum(exp(x-max)), deduping repeated states
// ---------------------------------------------------------------------------
__global__ __launch_bounds__(256) void row_max_kernel(
    const int* __restrict__ w2s, const float* __restrict__ L, unsigned* __restrict__ rowmax)
{
    __shared__ int st[8][32];
    int vl = threadIdx.x >> 5, k = threadIdx.x & 31;
    int v = blockIdx.x * 8 + vl;
    st[vl][k] = w2s[v * SPW + k];
    __syncthreads();
    int c = st[vl][k];
    bool dup = false;
    for (int kp = 0; kp < k; ++kp) if (st[vl][kp] == c) { dup = true; break; }
    if (!dup) atomicMax(&rowmax[c], enc_f(L[v * SPW + k]));
}

__global__ __launch_bounds__(256) void row_sum_kernel(
    const int* __restrict__ w2s, const float* __restrict__ L,
    const unsigned* __restrict__ rowmax, float* __restrict__ rowsum)
{
    __shared__ int st[8][32];
    int vl = threadIdx.x >> 5, k = threadIdx.x & 31;
    int v = blockIdx.x * 8 + vl;
    st[vl][k] = w2s[v * SPW + k];
    __syncthreads();
    int c = st[vl][k];
    bool dup = false;
    for (int kp = 0; kp < k; ++kp) if (st[vl][kp] == c) { dup = true; break; }
    if (!dup) atomicAdd(&rowsum[c], expf(L[v * SPW + k] - dec_f(rowmax[c])));
}

__global__ void denom_kernel(const unsigned* __restrict__ rowmax,
                             const float* __restrict__ rowsum, float* __restrict__ denom)
{
    int c = blockIdx.x * 256 + threadIdx.x;
    if (c >= C_) return;
    unsigned k = rowmax[c];
    denom[c] = (k == 0u) ? -INFINITY : (dec_f(k) + logf(rowsum[c]));
}

// ---------------------------------------------------------------------------
// K11: obs[n,t,k] = L[text[n,t],k] - denom[w2s[text[n,t],k]]
// ---------------------------------------------------------------------------
__global__ void obs_kernel(const int* __restrict__ text, const int* __restrict__ w2s,
                           const float* __restrict__ L, const float* __restrict__ denom,
                           float* __restrict__ obs)
{
    int idx = blockIdx.x * 256 + threadIdx.x;
    if (idx >= NB * TT * SPW) return;
    int k = idx & 31;
    int nt = idx >> 5;
    int v = text[nt];
    int c = w2s[v * SPW + k];
    obs[idx] = L[v * SPW + k] - denom[c];
}

// ---------------------------------------------------------------------------
// Inverted index build: bucket the NITEM (nt,i) row-uses by ci.
// ---------------------------------------------------------------------------
__global__ void hist_kernel(const int* __restrict__ text, const int* __restrict__ w2s,
                            int* __restrict__ count) {
    int item = blockIdx.x * 256 + threadIdx.x;
    int i  = item & 31;
    int nt = item >> 5;
    int t = nt >> 5, n = nt & 31;
    int v0 = text[n * TT + t];
    int ci = w2s[v0 * SPW + i];
    atomicAdd(&count[ci], 1);
}

__global__ __launch_bounds__(1024) void prefix_kernel(const int* __restrict__ count,
                                                      int* __restrict__ offs,
                                                      int* __restrict__ cursor) {
    __shared__ int buf[1024];
    int t = threadIdx.x;
    int c0 = count[t * 4 + 0], c1 = count[t * 4 + 1];
    int c2 = count[t * 4 + 2], c3 = count[t * 4 + 3];
    int s = c0 + c1 + c2 + c3;
    buf[t] = s;
    __syncthreads();
    for (int d = 1; d < 1024; d <<= 1) {
        int v = (t >= d) ? buf[t - d] : 0;
        __syncthreads();
        buf[t] += v;
        __syncthreads();
    }
    int excl = buf[t] - s;
    offs[t * 4 + 0] = excl; cursor[t * 4 + 0] = excl; excl += c0;
    offs[t * 4 + 1] = excl; cursor[t * 4 + 1] = excl; excl += c1;
    offs[t * 4 + 2] = excl; cursor[t * 4 + 2] = excl; excl += c2;
    offs[t * 4 + 3] = excl; cursor[t * 4 + 3] = excl;
    if (t == 1023) offs[4096] = buf[1023];
}

__global__ void fill_kernel(const int* __restrict__ text, const int* __restrict__ w2s,
                            int* __restrict__ cursor, int* __restrict__ entries) {
    int item = blockIdx.x * 256 + threadIdx.x;
    int i  = item & 31;
    int nt = item >> 5;
    int t = nt >> 5, n = nt & 31;
    int v0 = text[n * TT + t];
    int ci = w2s[v0 * SPW + i];
    int pos = atomicAdd(&cursor[ci], 1);
    entries[pos] = item;
}

// ---------------------------------------------------------------------------
// K12: phi gather, inverted: one block per TL row ci (LDS-staged, coalesced).
// phiN layout: [t, n, i, j]  (j innermost).
// ---------------------------------------------------------------------------
__global__ __launch_bounds__(256) void phi_gather_kernel(
    const float* __restrict__ TL, const int* __restrict__ offs, const int* __restrict__ entries,
    const float* __restrict__ lse1, const float* __restrict__ start_log,
    const float* __restrict__ obs, const int* __restrict__ text,
    const int* __restrict__ w2s, float* __restrict__ phiN)
{
    int ci = blockIdx.x;
    __shared__ float row[C_];   // 16 KB
    {
        const float4* src = (const float4*)(TL + (size_t)ci * C_);
        float4* dst = (float4*)row;
        for (int q = threadIdx.x; q < C_ / 4; q += 256) dst[q] = src[q];
    }
    __syncthreads();
    float abase = -lse1[ci];
    float st = start_log[ci];
    int beg = offs[ci], end = offs[ci + 1];
    int g = threadIdx.x >> 5, lane = threadIdx.x & 31;
    for (int idx = beg + g; idx < end; idx += 8) {
        int item = entries[idx];
        int i  = item & 31;
        int nt = item >> 5;
        int t = nt >> 5, n = nt & 31;
        int v1 = text[n * TT + t + 1];
        int cj = w2s[v1 * SPW + lane];
        float ob = obs[(size_t)(n * TT + t + 1) * SPW + lane];
        float a = abase;
        if (t == 0) a += st + obs[(size_t)(n * TT) * SPW + i];
        phiN[(size_t)nt * 1024 + i * 32 + lane] = row[cj] + a + ob;
    }
}

// ---------------------------------------------------------------------------
// K13: forward + backward scans (blocks 0..31 fwd, 32..63 bwd, concurrent).
// ---------------------------------------------------------------------------
__global__ __launch_bounds__(1024) void scan_kernel(
    const float* __restrict__ phiN, float* __restrict__ alphas_pre,
    float* __restrict__ betas_next, float* __restrict__ logZ, float* __restrict__ out)
{
    bool bwd = blockIdx.x >= NB;
    int n = blockIdx.x & (NB - 1);
    int tid = threadIdx.x;
    int a = tid >> 5, r = tid & 31;
    __shared__ float carry[32];
    if (tid < 32) carry[tid] = 0.f;
    __syncthreads();

    if (!bwd) {
        float pnext = phiN[(size_t)(0 * NB + n) * 1024 + r * 32 + a];
        for (int t = 0; t < TT - 1; ++t) {
            float cr = carry[r];
            float cold = (tid < 32) ? carry[tid] : 0.f;
            float p = pnext + cr;
            if (t + 1 < TT - 1)
                pnext = phiN[(size_t)((t + 1) * NB + n) * 1024 + r * 32 + a];
            float m = p;
#pragma unroll
            for (int off = 16; off; off >>= 1) m = fmaxf(m, __shfl_xor(m, off));
            float s = expf(p - m);
#pragma unroll
            for (int off = 16; off; off >>= 1) s += __shfl_xor(s, off);
            float nv = m + logf(s);
            if (tid < 32) alphas_pre[((size_t)t * NB + n) * SPW + tid] = cold;
            __syncthreads();
            if (r == 0) carry[a] = nv;
            __syncthreads();
        }
        if (tid < 32) {
            float x = carry[tid];
            float m = x;
#pragma unroll
            for (int off = 16; off; off >>= 1) m = fmaxf(m, __shfl_xor(m, off));
            float s = expf(x - m);
#pragma unroll
            for (int off = 16; off; off >>= 1) s += __shfl_xor(s, off);
            float lg = logf(s);
            if (tid == 0) logZ[n] = m + lg;
            out[2 + n * 32 + tid] = (x - m) - lg;
        }
    } else {
        float pnext = phiN[(size_t)((TT - 2) * NB + n) * 1024 + a * 32 + r];
        for (int t = TT - 2; t >= 0; --t) {
            float cr = carry[r];
            float cold = (tid < 32) ? carry[tid] : 0.f;
            float p = pnext + cr;
            if (t > 0)
                pnext = phiN[(size_t)((t - 1) * NB + n) * 1024 + a * 32 + r];
            float m = p;
#pragma unroll
            for (int off = 16; off; off >>= 1) m = fmaxf(m, __shfl_xor(m, off));
            float s = expf(p - m);
#pragma unroll
            for (int off = 16; off; off >>= 1) s += __shfl_xor(s, off);
            float nv = m + logf(s);
            if (tid < 32) betas_next[((size_t)t * NB + n) * SPW + tid] = cold;
            __syncthreads();
            if (r == 0) carry[a] = nv;
            __syncthreads();
        }
    }
}

// ---------------------------------------------------------------------------
// K14: elbo = sum exp(ap[i] + phi + bn[j] - logZ) * phi, double accumulation
// ---------------------------------------------------------------------------
__global__ __launch_bounds__(256) void elbo_kernel(
    const float* __restrict__ phiN, const float* __restrict__ alphas_pre,
    const float* __restrict__ betas_next, const float* __restrict__ logZ,
    double* __restrict__ elbo_acc)
{
    int t = blockIdx.x / NB;
    int n = blockIdx.x - t * NB;
    int tid = threadIdx.x;
    __shared__ float ap[32], bn[32];
    if (tid < 32) ap[tid] = alphas_pre[((size_t)t * NB + n) * SPW + tid];
    else if (tid < 64) bn[tid - 32] = betas_next[((size_t)t * NB + n) * SPW + (tid - 32)];
    __syncthreads();
    float lz = logZ[n];
    size_t base = (size_t)(t * NB + n) * 1024;
    double local = 0.0;
#pragma unroll
    for (int e = tid; e < 1024; e += 256) {
        int i = e >> 5, j = e & 31;
        float ph = phiN[base + e];
        float lm = ap[i] + ph + bn[j] - lz;
        local += (double)(expf(lm) * ph);
    }
#pragma unroll
    for (int off = 32; off; off >>= 1) local += __shfl_down(local, off);
    __shared__ double wsum[4];
    if ((tid & 63) == 0) wsum[tid >> 6] = local;
    __syncthreads();
    if (tid == 0) atomicAdd(elbo_acc, wsum[0] + wsum[1] + wsum[2] + wsum[3]);
}

// K15: finalize scalar outputs
__global__ void finalize_kernel(const double* __restrict__ elbo_acc,
                                const float* __restrict__ logZ, float* __restrict__ out)
{
    if (threadIdx.x == 0) {
        out[0] = (float)(*elbo_acc);
        float s = 0.f;
        for (int n = 0; n < NB; ++n) s += logZ[n];
        out[1] = s;
    }
}

// ---------------------------------------------------------------------------
extern "C" void kernel_launch(void* const* d_in, const int* in_sizes, int n_in,
                              void* d_out, int out_size, void* d_ws, size_t ws_size,
                              hipStream_t stream) {
    (void)in_sizes; (void)n_in; (void)out_size; (void)ws_size;
    const float* start_emb = (const float*)d_in[0];
    const float* sw1  = (const float*)d_in[1];
    const float* sb1  = (const float*)d_in[2];
    const float* sw2  = (const float*)d_in[3];
    const float* sb2  = (const float*)d_in[4];
    const float* sow  = (const float*)d_in[5];
    const float* sob  = (const float*)d_in[6];
    const float* state_emb = (const float*)d_in[7];
    const float* tw1  = (const float*)d_in[8];
    const float* tb1  = (const float*)d_in[9];
    const float* tw2  = (const float*)d_in[10];
    const float* tb2  = (const float*)d_in[11];
    const float* nsp  = (const float*)d_in[12];
    const float* pre_emb = (const float*)d_in[13];
    const float* ew1  = (const float*)d_in[14];
    const float* eb1  = (const float*)d_in[15];
    const float* ew2  = (const float*)d_in[16];
    const float* eb2  = (const float*)d_in[17];
    const float* eow  = (const float*)d_in[18];
    const float* eob  = (const float*)d_in[19];
    const int*   text = (const int*)d_in[20];
    const int*   w2s  = (const int*)d_in[21];

    float* ws = (float*)d_ws;
    float* TL      = ws + OFF_TL;
    float* res_t   = ws + OFF_RES;
    float* res_s   = ws + OFF_RES_S;
    float* res_e   = ws + OFF_RES_E;
    float* s_tmp   = ws + OFF_STMP;
    float* startl  = ws + OFF_START;
    float* lse1    = ws + OFF_LSE1;
    unsigned* rmax = (unsigned*)(ws + OFF_RMAX);
    float* rsum    = ws + OFF_RSUM;
    float* den     = ws + OFF_DEN;
    float* logZ    = ws + OFF_LOGZ;
    double* elboA  = (double*)(ws + OFF_ELBO);
    unsigned short* Ap = (unsigned short*)(ws + OFF_AP);
    unsigned short* Bp = (unsigned short*)(ws + OFF_BP);
    float* ewT     = ws + OFF_EWT;
    float* Lm      = ws + OFF_L;
    float* obs     = ws + OFF_OBS;
    float* phiN    = ws + OFF_PHI;
    float* alph    = ws + OFF_ALPH;
    float* beta    = ws + OFF_BETA;
    int* cnt       = (int*)(ws + OFF_CNT);
    int* offs      = (int*)(ws + OFF_OFFS);
    int* cur       = (int*)(ws + OFF_CUR);
    int* ent       = (int*)(ws + OFF_ENT);
    float* out     = (float*)d_out;

    init_kernel<<<16, 256, 0, stream>>>(rmax, rsum, cnt, elboA);

    // all three residual MLPs in one launch
    ResArgs rs = {start_emb, sw1, sb1, sw2, sb2, res_s};
    ResArgs rt = {state_emb, tw1, tb1, tw2, tb2, res_t};
    ResArgs re = {pre_emb,   ew1, eb1, ew2, eb2, res_e};
    residual3_kernel<<<768, 256, 0, stream>>>(rs, rt, re);

    // start path
    start_head_kernel<<<C_ / 4, 256, 0, stream>>>(res_s, sow, sob, s_tmp);
    logsoftmax_start_kernel<<<1, 1024, 0, stream>>>(s_tmp, startl);

    // transition path: split-fp16 MFMA GEMM, then single row-lse
    convert_kernel<<<2 * C_ * H_ / 4 / 256, 256, 0, stream>>>(res_t, nsp, Ap, Bp);
    gemm_bt_kernel<<<dim3(32, 32), 256, 0, stream>>>(Ap, Bp, TL);
    row_lse_kernel<<<C_, 256, 0, stream>>>(TL, lse1);

    // emission path (sparse: only the V*SPW masked entries)
    transpose_kernel<<<dim3(V_ / 32, H_ / 32), 256, 0, stream>>>(eow, ewT);
    em_logits_kernel<<<V_, 256, 0, stream>>>(res_e, ewT, eob, w2s, Lm);
    row_max_kernel<<<V_ / 8, 256, 0, stream>>>(w2s, Lm, rmax);
    row_sum_kernel<<<V_ / 8, 256, 0, stream>>>(w2s, Lm, rmax, rsum);
    denom_kernel<<<16, 256, 0, stream>>>(rmax, rsum, den);
    obs_kernel<<<(NB * TT * SPW) / 256, 256, 0, stream>>>(text, w2s, Lm, den, obs);

    // inverted index (aliased onto alpha/beta region — dead until scan)
    hist_kernel<<<NITEM / 256, 256, 0, stream>>>(text, w2s, cnt);
    prefix_kernel<<<1, 1024, 0, stream>>>(cnt, offs, cur);
    fill_kernel<<<NITEM / 256, 256, 0, stream>>>(text, w2s, cur, ent);

    // phi assembly + scans + outputs
    phi_gather_kernel<<<C_, 256, 0, stream>>>(TL, offs, ent, lse1, startl,
                                              obs, text, w2s, phiN);
    scan_kernel<<<2 * NB, 1024, 0, stream>>>(phiN, alph, beta, logZ, out);
    elbo_kernel<<<(TT - 1) * NB, 256, 0, stream>>>(phiN, alph, beta, logZ, elboA);
    finalize_kernel<<<1, 64, 0, stream>>>(elboA, logZ, out);
}

// Round 4
// 591.435 us; speedup vs baseline: 1.2864x; 1.2115x over previous
//
#include <hip/hip_runtime.h>
#include <hip/hip_fp16.h>
#include <math.h>

// Problem constants (fixed by the reference)
#define C_   4096
#define H_   256
#define V_   16000
#define SPW  32
#define NB   32    // N (batch)
#define TT   128   // T (sequence length)
#define NTOK ((TT - 1) * NB)          // 4064 token transitions
#define NITEM (NTOK * SPW)            // 130048 (nt, i) row-uses
#define GEMM_K 768                    // 3 x 256 split-fp16 segments

// ---------------------------------------------------------------------------
// Workspace layout (float offsets). Total ~27.0M floats = ~108 MB.
// ---------------------------------------------------------------------------
static const size_t OFF_TL    = 0;                                   // C*C transition logits
static const size_t OFF_RES   = OFF_TL   + (size_t)C_ * C_;          // C*H (unused spare)
static const size_t OFF_STMP  = OFF_RES  + (size_t)C_ * H_;          // C   start pre-softmax
static const size_t OFF_START = OFF_STMP + C_;                       // C   start log-probs
static const size_t OFF_LSE1  = OFF_START + C_;                      // C
static const size_t OFF_LSE2  = OFF_LSE1 + C_;                       // C (spare)
static const size_t OFF_RMAX  = OFF_LSE2 + C_;                       // C (unsigned, encoded-float max)
static const size_t OFF_RSUM  = OFF_RMAX + C_;                       // C
static const size_t OFF_DEN   = OFF_RSUM + C_;                       // C emission row log-denominator
static const size_t OFF_LOGZ  = OFF_DEN  + C_;                       // NB floats + counter at +40
static const size_t OFF_ELBO  = OFF_LOGZ + 64;                       // double accumulator
static const size_t OFF_EWT   = OFF_ELBO + 16;                       // V*H region (Ap/Bp early, ewT later)
static const size_t OFF_L     = OFF_EWT  + (size_t)V_ * H_;          // V*SPW masked emission logits
static const size_t OFF_OBS   = OFF_L    + (size_t)V_ * SPW;         // N*T*SPW
static const size_t OFF_PHI   = OFF_OBS  + (size_t)NB * TT * SPW;    // (T-1)*N*SPW*SPW  phiN[t,n,i,j]
static const size_t OFF_ALPH  = OFF_PHI  + (size_t)NTOK * SPW * SPW; // (T-1)*N*SPW
static const size_t OFF_BETA  = OFF_ALPH + (size_t)NTOK * SPW;       // (T-1)*N*SPW

// MLP GEMM scratch aliased onto TL region (dead until gemm_bt writes TL):
static const size_t OFF_XP    = OFF_TL;                                   // 12288x768 us
static const size_t OFF_HP    = OFF_TL + (size_t)3 * C_ * GEMM_K / 2;     // 12288x768 us
static const size_t OFF_W1P   = OFF_TL + (size_t)6 * C_ * GEMM_K / 2;     // 3 x 256x768 us
static const size_t OFF_W2P   = OFF_W1P + (size_t)3 * 256 * GEMM_K / 2;

// Ap/Bp (TL-GEMM operands) aliased onto ewT region (ewT live only
// transpose -> em_logits, which run after gemm_bt).
static const size_t OFF_AP    = OFF_EWT;                              // 4096x768 us
static const size_t OFF_BP    = OFF_EWT + (size_t)C_ * GEMM_K / 2;    // 4096x768 us

// res_e aliased onto phi region (phi written much later by phi_gather).
static const size_t OFF_RES_E = OFF_PHI + (size_t)C_ * H_;

// Inverted-index scratch aliased onto alpha/beta region (dead until scan).
static const size_t OFF_CNT   = OFF_ALPH;            // 4096 int
static const size_t OFF_OFFS  = OFF_ALPH + 4096;     // 4097 int (pad to 4112)
static const size_t OFF_CUR   = OFF_ALPH + 8208;     // 4096 int
static const size_t OFF_ENT   = OFF_ALPH + 12304;    // NITEM int

// Monotone float<->uint encoding for atomicMax on floats (handles negatives)
__device__ inline unsigned enc_f(float f) {
    unsigned u = __float_as_uint(f);
    return (u & 0x80000000u) ? ~u : (u | 0x80000000u);
}
__device__ inline float dec_f(unsigned k) {
    return (k & 0x80000000u) ? __uint_as_float(k ^ 0x80000000u) : __uint_as_float(~k);
}

__device__ inline void split_h(float v, unsigned short& hi, unsigned short& lo) {
    __half h = __float2half(v);
    __half l = __float2half(v - __half2float(h));
    __builtin_memcpy(&hi, &h, 2);
    __builtin_memcpy(&lo, &l, 2);
}

typedef __attribute__((ext_vector_type(8))) short short8;
typedef __attribute__((ext_vector_type(4))) float floatx4;

#define GLB(p)  ((const __attribute__((address_space(1))) unsigned int*)(p))
#define LDSP(p) ((__attribute__((address_space(3))) unsigned int*)(p))

// ---------------------------------------------------------------------------
// K0: init accumulators (ws is poisoned each call)
// ---------------------------------------------------------------------------
__global__ void init_kernel(unsigned* __restrict__ rowmax, float* __restrict__ rowsum,
                            int* __restrict__ cnt, float* __restrict__ s_tmp,
                            unsigned* __restrict__ done_cnt, double* __restrict__ elbo_acc) {
    int i = blockIdx.x * 256 + threadIdx.x;
    if (i < C_) { rowmax[i] = 0u; rowsum[i] = 0.f; cnt[i] = 0; s_tmp[i] = 0.f; }
    if (i == 0) { *elbo_acc = 0.0; *done_cnt = 0u; }
}

// ---------------------------------------------------------------------------
// K1: pack everything to split-fp16.
//   blocks [0,3072):   X = [start_emb; state_emb; pre_emb] -> Xp  [hi|lo|hi]
//   blocks [3072,4096): nsp -> Bp                               [hi|hi|lo]
//   blocks [4096,4480): 6 weight matrices, transposed -> W1p/W2p [hi|hi|lo]
// ---------------------------------------------------------------------------
__global__ __launch_bounds__(256) void pack_all_kernel(
    const float* __restrict__ se, const float* __restrict__ ste, const float* __restrict__ pe,
    const float* __restrict__ nsp,
    const float* __restrict__ w1_0, const float* __restrict__ w1_1, const float* __restrict__ w1_2,
    const float* __restrict__ w2_0, const float* __restrict__ w2_1, const float* __restrict__ w2_2,
    unsigned short* __restrict__ Xp, unsigned short* __restrict__ Bp,
    unsigned short* __restrict__ W1p, unsigned short* __restrict__ W2p)
{
    __shared__ float tile_s[32][33];
    int blk = blockIdx.x;
    if (blk < 4096) {
        bool isB = blk >= 3072;
        int e4 = (isB ? blk - 3072 : blk) * 256 + threadIdx.x;
        int r = e4 >> 6;                 // row (12288 for X, 4096 for B)
        int c = (e4 & 63) * 4;
        const float* src;
        unsigned short* dst;
        if (isB) { src = nsp + (size_t)r * H_; dst = Bp; }
        else {
            int inst = r >> 12;
            int rl = r & 4095;
            src = (inst == 0 ? se : inst == 1 ? ste : pe) + (size_t)rl * H_;
            dst = Xp;
        }
        float4 v = *(const float4*)(src + c);
        float vv[4] = {v.x, v.y, v.z, v.w};
        union { unsigned short s[4]; ushort4 u; } hi, lo;
#pragma unroll
        for (int q = 0; q < 4; ++q) split_h(vv[q], hi.s[q], lo.s[q]);
        size_t base = (size_t)r * GEMM_K + c;
        if (!isB) {   // A-layout [hi | lo | hi]
            *(ushort4*)&dst[base]       = hi.u;
            *(ushort4*)&dst[base + 256] = lo.u;
            *(ushort4*)&dst[base + 512] = hi.u;
        } else {      // B-layout [hi | hi | lo]
            *(ushort4*)&dst[base]       = hi.u;
            *(ushort4*)&dst[base + 256] = hi.u;
            *(ushort4*)&dst[base + 512] = lo.u;
        }
    } else {
        int b = blk - 4096;              // 0..383
        int mat = b >> 6, tile = b & 63;
        int n0 = (tile & 7) * 32, k0 = (tile >> 3) * 32;
        const float* W = mat == 0 ? w1_0 : mat == 1 ? w1_1 : mat == 2 ? w1_2
                       : mat == 3 ? w2_0 : mat == 4 ? w2_1 : w2_2;
        unsigned short* dst = (mat < 3) ? W1p + (size_t)mat * 256 * GEMM_K
                                        : W2p + (size_t)(mat - 3) * 256 * GEMM_K;
        int tx = threadIdx.x & 31, ty = threadIdx.x >> 5;   // ty 0..7
#pragma unroll
        for (int q = 0; q < 4; ++q)
            tile_s[ty + 8 * q][tx] = W[(size_t)(k0 + ty + 8 * q) * 256 + n0 + tx];
        __syncthreads();
#pragma unroll
        for (int q = 0; q < 4; ++q) {
            float v = tile_s[tx][ty + 8 * q];     // W[k0+tx][n0+ty+8q]
            unsigned short hi, lo;
            split_h(v, hi, lo);
            size_t ob = (size_t)(n0 + ty + 8 * q) * GEMM_K + k0 + tx;
            dst[ob] = hi; dst[ob + 256] = hi; dst[ob + 512] = lo;
        }
    }
}

// ---------------------------------------------------------------------------
// Shared GEMM core: 128x128 tile, 4 waves of 64x64, f16 16x16x32 MFMA, K=768.
// ---------------------------------------------------------------------------
#define GEMM_PROLOGUE(APTR, BPTR)                                              \
    __shared__ __align__(16) unsigned short As[128 * 64];                      \
    __shared__ __align__(16) unsigned short Bs[128 * 64];                      \
    int tid = threadIdx.x;                                                     \
    int wave = tid >> 6, lane = tid & 63;                                      \
    int wm = (wave & 1) * 64, wn = (wave >> 1) * 64;                           \
    int l15 = lane & 15, quad = lane >> 4;                                     \
    floatx4 acc[4][4] = {};                                                    \
    int c0row = tid >> 3;                                                      \
    int c0col = (tid & 7) * 8;                                                 \
    for (int k0 = 0; k0 < GEMM_K; k0 += 64) {                                  \
        __syncthreads();                                                       \
        _Pragma("unroll")                                                      \
        for (int q = 0; q < 4; ++q) {                                          \
            int row = c0row + q * 32;                                          \
            const unsigned short* ga = (APTR) + (size_t)(i0 + row) * GEMM_K + k0 + c0col; \
            const unsigned short* gb = (BPTR) + (size_t)(j0 + row) * GEMM_K + k0 + c0col; \
            __builtin_amdgcn_global_load_lds(GLB(ga), LDSP(&As[(size_t)row * 64 + c0col]), 16, 0, 0); \
            __builtin_amdgcn_global_load_lds(GLB(gb), LDSP(&Bs[(size_t)row * 64 + c0col]), 16, 0, 0); \
        }                                                                      \
        __syncthreads();                                                       \
        _Pragma("unroll")                                                      \
        for (int ks = 0; ks < 64; ks += 32) {                                  \
            short8 af[4], bfr[4];                                              \
            _Pragma("unroll")                                                  \
            for (int mi = 0; mi < 4; ++mi)                                     \
                af[mi] = *(const short8*)&As[(wm + mi * 16 + l15) * 64 + ks + quad * 8]; \
            _Pragma("unroll")                                                  \
            for (int ni = 0; ni < 4; ++ni)                                     \
                bfr[ni] = *(const short8*)&Bs[(wn + ni * 16 + l15) * 64 + ks + quad * 8]; \
            _Pragma("unroll")                                                  \
            for (int mi = 0; mi < 4; ++mi)                                     \
                _Pragma("unroll")                                              \
                for (int ni = 0; ni < 4; ++ni)                                 \
                    acc[mi][ni] = __builtin_amdgcn_mfma_f32_16x16x32_f16(      \
                        af[mi], bfr[ni], acc[mi][ni], 0, 0, 0);                \
        }                                                                      \
    }

// ---------------------------------------------------------------------------
// K2: MLP layer 1: H = relu(X@W1 + b1), output packed split-fp16 (A-layout).
// grid (2, 96): j in {0,128}, i over 12288 rows; instance = i-tile >> 5.
// ---------------------------------------------------------------------------
__global__ __launch_bounds__(256) void gemm_layer1(
    const unsigned short* __restrict__ Xp, const unsigned short* __restrict__ Wp,
    const float* __restrict__ b0, const float* __restrict__ b1, const float* __restrict__ b2,
    unsigned short* __restrict__ Hp)
{
    int i0 = blockIdx.y * 128, j0 = blockIdx.x * 128;
    int inst = blockIdx.y >> 5;
    const unsigned short* Wbase = Wp + (size_t)inst * 256 * GEMM_K;
    const float* bias = inst == 0 ? b0 : (inst == 1 ? b1 : b2);
    GEMM_PROLOGUE(Xp, Wbase - (size_t)j0 * GEMM_K + (size_t)j0 * GEMM_K)   // B rows indexed j0+row
#pragma unroll
    for (int mi = 0; mi < 4; ++mi) {
#pragma unroll
        for (int reg = 0; reg < 4; ++reg) {
            int row = i0 + wm + mi * 16 + quad * 4 + reg;
#pragma unroll
            for (int ni = 0; ni < 4; ++ni) {
                int col = j0 + wn + ni * 16 + l15;
                float h = fmaxf(acc[mi][ni][reg] + bias[col], 0.f);
                unsigned short hi, lo;
                split_h(h, hi, lo);
                size_t base = (size_t)row * GEMM_K + col;
                Hp[base] = hi; Hp[base + 256] = lo; Hp[base + 512] = hi;
            }
        }
    }
}

// ---------------------------------------------------------------------------
// K3: MLP layer 2: Z = relu(H@W2 + b2) + X.  Per-instance epilogue:
//   inst 0 (start): accumulate s_tmp[row] += sum_col Z*sow[col] (atomics)
//   inst 1 (trans): pack Z -> Ap (split-fp16 A-layout) for the TL GEMM
//   inst 2 (emit):  store fp32 res_e for em_logits
// ---------------------------------------------------------------------------
__global__ __launch_bounds__(256) void gemm_layer2(
    const unsigned short* __restrict__ Hp, const unsigned short* __restrict__ Wp,
    const float* __restrict__ b0, const float* __restrict__ b1, const float* __restrict__ b2,
    const float* __restrict__ x0, const float* __restrict__ x1, const float* __restrict__ x2,
    const float* __restrict__ sow, float* __restrict__ s_tmp,
    unsigned short* __restrict__ Ap, float* __restrict__ res_e)
{
    int i0 = blockIdx.y * 128, j0 = blockIdx.x * 128;
    int inst = blockIdx.y >> 5;
    const unsigned short* Wbase = Wp + (size_t)inst * 256 * GEMM_K;
    const float* bias = inst == 0 ? b0 : (inst == 1 ? b1 : b2);
    const float* X = inst == 0 ? x0 : (inst == 1 ? x1 : x2);
    GEMM_PROLOGUE(Hp, Wbase)
#pragma unroll
    for (int mi = 0; mi < 4; ++mi) {
#pragma unroll
        for (int reg = 0; reg < 4; ++reg) {
            int row = i0 + wm + mi * 16 + quad * 4 + reg;
            int rl = row & 4095;
            float ps = 0.f;
#pragma unroll
            for (int ni = 0; ni < 4; ++ni) {
                int col = j0 + wn + ni * 16 + l15;
                float z = fmaxf(acc[mi][ni][reg] + bias[col], 0.f)
                        + X[(size_t)rl * H_ + col];
                if (inst == 0) {
                    ps += z * sow[col];
                } else if (inst == 1) {
                    unsigned short hi, lo;
                    split_h(z, hi, lo);
                    size_t base = (size_t)rl * GEMM_K + col;
                    Ap[base] = hi; Ap[base + 256] = lo; Ap[base + 512] = hi;
                } else {
                    res_e[(size_t)rl * H_ + col] = z;
                }
            }
            if (inst == 0) {
                ps += __shfl_xor(ps, 1);
                ps += __shfl_xor(ps, 2);
                ps += __shfl_xor(ps, 4);
                ps += __shfl_xor(ps, 8);
                if (l15 == 0) atomicAdd(&s_tmp[rl], ps);
            }
        }
    }
}

// ---------------------------------------------------------------------------
// K4: log_softmax over C=4096 in one block (s_out_b cancels in log_softmax)
// ---------------------------------------------------------------------------
__global__ __launch_bounds__(1024) void logsoftmax_start_kernel(
    const float* __restrict__ s_tmp, float* __restrict__ out)
{
    __shared__ float red_m[16];
    __shared__ float red_s[16];
    int t = threadIdx.x;
    float v[4];
    float m = -INFINITY;
#pragma unroll
    for (int q = 0; q < 4; ++q) { v[q] = s_tmp[t + q * 1024]; m = fmaxf(m, v[q]); }
#pragma unroll
    for (int off = 32; off; off >>= 1) m = fmaxf(m, __shfl_xor(m, off));
    if ((t & 63) == 0) red_m[t >> 6] = m;
    __syncthreads();
    float M = red_m[0];
#pragma unroll
    for (int w = 1; w < 16; ++w) M = fmaxf(M, red_m[w]);
    float s = 0.f;
#pragma unroll
    for (int q = 0; q < 4; ++q) s += expf(v[q] - M);
#pragma unroll
    for (int off = 32; off; off >>= 1) s += __shfl_xor(s, off);
    if ((t & 63) == 0) red_s[t >> 6] = s;
    __syncthreads();
    float S = 0.f;
#pragma unroll
    for (int w = 0; w < 16; ++w) S += red_s[w];
    float lg = logf(S);
#pragma unroll
    for (int q = 0; q < 4; ++q) out[t + q * 1024] = (v[q] - M) - lg;
}

// ---------------------------------------------------------------------------
// K5: TL = Ap.Bp^T  (split-fp16 MFMA NT-GEMM, K=768), fp32 out.
// ---------------------------------------------------------------------------
__global__ __launch_bounds__(256) void gemm_bt_kernel(
    const unsigned short* __restrict__ Ap, const unsigned short* __restrict__ Bp,
    float* __restrict__ Cmat)
{
    int i0 = blockIdx.y * 128, j0 = blockIdx.x * 128;
    GEMM_PROLOGUE(Ap, Bp)
    // C/D layout: col = lane&15, row = quad*4 + reg  [m89-verified]
#pragma unroll
    for (int mi = 0; mi < 4; ++mi) {
#pragma unroll
        for (int reg = 0; reg < 4; ++reg) {
            int row = i0 + wm + mi * 16 + quad * 4 + reg;
            float* crow = Cmat + (size_t)row * C_ + j0 + wn;
#pragma unroll
            for (int ni = 0; ni < 4; ++ni)
                crow[ni * 16 + l15] = acc[mi][ni][reg];
        }
    }
}

// ---------------------------------------------------------------------------
// K6: per-row online logsumexp over C columns
// ---------------------------------------------------------------------------
__global__ __launch_bounds__(256) void row_lse_kernel(
    const float* __restrict__ TL, float* __restrict__ out_lse)
{
    int i = blockIdx.x;
    int t = threadIdx.x;
    const float* row = TL + (size_t)i * C_;
    float m = -INFINITY, s = 0.f;
    for (int j = t; j < C_; j += 256) {
        float x = row[j];
        float nm = fmaxf(m, x);
        s = s * expf(m - nm) + expf(x - nm);
        m = nm;
    }
#pragma unroll
    for (int off = 32; off; off >>= 1) {
        float om = __shfl_xor(m, off);
        float os = __shfl_xor(s, off);
        float nm = fmaxf(m, om);
        s = s * expf(m - nm) + os * expf(om - nm);
        m = nm;
    }
    __shared__ float sm[4], ss[4];
    if ((t & 63) == 0) { sm[t >> 6] = m; ss[t >> 6] = s; }
    __syncthreads();
    if (t == 0) {
        float M = sm[0], S = ss[0];
#pragma unroll
        for (int w = 1; w < 4; ++w) {
            float nm = fmaxf(M, sm[w]);
            S = S * expf(M - nm) + ss[w] * expf(sm[w] - nm);
            M = nm;
        }
        out_lse[i] = M + logf(S);
    }
}

// ---------------------------------------------------------------------------
// K7: transpose e_out_w (H,V) -> ewT (V,H)
// ---------------------------------------------------------------------------
__global__ __launch_bounds__(256) void transpose_kernel(
    const float* __restrict__ W, float* __restrict__ WT)
{
    __shared__ float tile[32][33];
    int tx = threadIdx.x & 31, ty = threadIdx.x >> 5;
    int v0 = blockIdx.x * 32, h0 = blockIdx.y * 32;
#pragma unroll
    for (int q = 0; q < 4; ++q)
        tile[ty + 8 * q][tx] = W[(size_t)(h0 + ty + 8 * q) * V_ + v0 + tx];
    __syncthreads();
#pragma unroll
    for (int q = 0; q < 4; ++q)
        WT[(size_t)(v0 + ty + 8 * q) * H_ + h0 + tx] = tile[tx][ty + 8 * q];
}

// ---------------------------------------------------------------------------
// K8: masked emission logits, float4 dots (8 lanes x float4 per (v,k))
// ---------------------------------------------------------------------------
__global__ __launch_bounds__(256) void em_logits_kernel(
    const float* __restrict__ res_pre, const float* __restrict__ ewT,
    const float* __restrict__ eob, const int* __restrict__ w2s, float* __restrict__ L)
{
    int v = blockIdx.x;
    __shared__ __align__(16) float wv[H_];
    wv[threadIdx.x] = ewT[(size_t)v * H_ + threadIdx.x];
    __syncthreads();
    int g = threadIdx.x >> 3;
    int l = threadIdx.x & 7;
    int c = w2s[v * SPW + g];
    const float4* row4 = (const float4*)(res_pre + (size_t)c * H_);
    const float4* wv4 = (const float4*)wv;
    float sum = 0.f;
#pragma unroll
    for (int m = 0; m < 8; ++m) {
        float4 r = row4[l + m * 8];
        float4 w = wv4[l + m * 8];
        sum += r.x * w.x + r.y * w.y + r.z * w.z + r.w * w.w;
    }
    sum += __shfl_xor(sum, 1);
    sum += __shfl_xor(sum, 2);
    sum += __shfl_xor(sum, 4);
    if (l == 0) L[v * SPW + g] = sum + eob[v];
}

// ---------------------------------------------------------------------------
// K9/K10: scatter per-state max, then sum(exp(x-max)), deduping repeated states
// ---------------------------------------------------------------------------
__global__ __launch_bounds__(256) void row_max_kernel(
    const int* __restrict__ w2s, const float* __restrict__ L, unsigned* __restrict__ rowmax)
{
    __shared__ int st[8][32];
    int vl = threadIdx.x >> 5, k = threadIdx.x & 31;
    int v = blockIdx.x * 8 + vl;
    st[vl][k] = w2s[v * SPW + k];
    __syncthreads();
    int c = st[vl][k];
    bool dup = false;
    for (int kp = 0; kp < k; ++kp) if (st[vl][kp] == c) { dup = true; break; }
    if (!dup) atomicMax(&rowmax[c], enc_f(L[v * SPW + k]));
}

__global__ __launch_bounds__(256) void row_sum_kernel(
    const int* __restrict__ w2s, const float* __restrict__ L,
    const unsigned* __restrict__ rowmax, float* __restrict__ rowsum)
{
    __shared__ int st[8][32];
    int vl = threadIdx.x >> 5, k = threadIdx.x & 31;
    int v = blockIdx.x * 8 + vl;
    st[vl][k] = w2s[v * SPW + k];
    __syncthreads();
    int c = st[vl][k];
    bool dup = false;
    for (int kp = 0; kp < k; ++kp) if (st[vl][kp] == c) { dup = true; break; }
    if (!dup) atomicAdd(&rowsum[c], expf(L[v * SPW + k] - dec_f(rowmax[c])));
}

// ---------------------------------------------------------------------------
// K11: fused denom (blocks 0..15) + inverted-index histogram (blocks 16..523)
// ---------------------------------------------------------------------------
__global__ void denom_hist_kernel(const unsigned* __restrict__ rowmax,
                                  const float* __restrict__ rowsum, float* __restrict__ denom,
                                  const int* __restrict__ text, const int* __restrict__ w2s,
                                  int* __restrict__ count)
{
    if (blockIdx.x < 16) {
        int c = blockIdx.x * 256 + threadIdx.x;
        unsigned k = rowmax[c];
        denom[c] = (k == 0u) ? -INFINITY : (dec_f(k) + logf(rowsum[c]));
    } else {
        int item = (blockIdx.x - 16) * 256 + threadIdx.x;
        int i  = item & 31;
        int nt = item >> 5;
        int t = nt >> 5, n = nt & 31;
        int v0 = text[n * TT + t];
        int ci = w2s[v0 * SPW + i];
        atomicAdd(&count[ci], 1);
    }
}

__global__ __launch_bounds__(1024) void prefix_kernel(const int* __restrict__ count,
                                                      int* __restrict__ offs,
                                                      int* __restrict__ cursor) {
    __shared__ int buf[1024];
    int t = threadIdx.x;
    int c0 = count[t * 4 + 0], c1 = count[t * 4 + 1];
    int c2 = count[t * 4 + 2], c3 = count[t * 4 + 3];
    int s = c0 + c1 + c2 + c3;
    buf[t] = s;
    __syncthreads();
    for (int d = 1; d < 1024; d <<= 1) {
        int v = (t >= d) ? buf[t - d] : 0;
        __syncthreads();
        buf[t] += v;
        __syncthreads();
    }
    int excl = buf[t] - s;
    offs[t * 4 + 0] = excl; cursor[t * 4 + 0] = excl; excl += c0;
    offs[t * 4 + 1] = excl; cursor[t * 4 + 1] = excl; excl += c1;
    offs[t * 4 + 2] = excl; cursor[t * 4 + 2] = excl; excl += c2;
    offs[t * 4 + 3] = excl; cursor[t * 4 + 3] = excl;
    if (t == 1023) offs[4096] = buf[1023];
}

// ---------------------------------------------------------------------------
// K13: fused obs (blocks 0..511) + index fill (blocks 512..1019)
// ---------------------------------------------------------------------------
__global__ void obs_fill_kernel(const int* __restrict__ text, const int* __restrict__ w2s,
                                const float* __restrict__ L, const float* __restrict__ denom,
                                float* __restrict__ obs,
                                int* __restrict__ cursor, int* __restrict__ entries)
{
    if (blockIdx.x < 512) {
        int idx = blockIdx.x * 256 + threadIdx.x;
        int k = idx & 31;
        int nt = idx >> 5;
        int v = text[nt];
        int c = w2s[v * SPW + k];
        obs[idx] = L[v * SPW + k] - denom[c];
    } else {
        int item = (blockIdx.x - 512) * 256 + threadIdx.x;
        int i  = item & 31;
        int nt = item >> 5;
        int t = nt >> 5, n = nt & 31;
        int v0 = text[n * TT + t];
        int ci = w2s[v0 * SPW + i];
        int pos = atomicAdd(&cursor[ci], 1);
        entries[pos] = item;
    }
}

// ---------------------------------------------------------------------------
// K14: phi gather, inverted: one block per TL row ci (LDS-staged, coalesced).
// phiN layout: [t, n, i, j]  (j innermost).
// ---------------------------------------------------------------------------
__global__ __launch_bounds__(256) void phi_gather_kernel(
    const float* __restrict__ TL, const int* __restrict__ offs, const int* __restrict__ entries,
    const float* __restrict__ lse1, const float* __restrict__ start_log,
    const float* __restrict__ obs, const int* __restrict__ text,
    const int* __restrict__ w2s, float* __restrict__ phiN)
{
    int ci = blockIdx.x;
    __shared__ float row[C_];   // 16 KB
    {
        const float4* src = (const float4*)(TL + (size_t)ci * C_);
        float4* dst = (float4*)row;
        for (int q = threadIdx.x; q < C_ / 4; q += 256) dst[q] = src[q];
    }
    __syncthreads();
    float abase = -lse1[ci];
    float st = start_log[ci];
    int beg = offs[ci], end = offs[ci + 1];
    int g = threadIdx.x >> 5, lane = threadIdx.x & 31;
    for (int idx = beg + g; idx < end; idx += 8) {
        int item = entries[idx];
        int i  = item & 31;
        int nt = item >> 5;
        int t = nt >> 5, n = nt & 31;
        int v1 = text[n * TT + t + 1];
        int cj = w2s[v1 * SPW + lane];
        float ob = obs[(size_t)(n * TT + t + 1) * SPW + lane];
        float a = abase;
        if (t == 0) a += st + obs[(size_t)(n * TT) * SPW + i];
        phiN[(size_t)nt * 1024 + i * 32 + lane] = row[cj] + a + ob;
    }
}

// ---------------------------------------------------------------------------
// K15: forward + backward scans (blocks 0..31 fwd, 32..63 bwd, concurrent).
// ---------------------------------------------------------------------------
__global__ __launch_bounds__(1024) void scan_kernel(
    const float* __restrict__ phiN, float* __restrict__ alphas_pre,
    float* __restrict__ betas_next, float* __restrict__ logZ, float* __restrict__ out)
{
    bool bwd = blockIdx.x >= NB;
    int n = blockIdx.x & (NB - 1);
    int tid = threadIdx.x;
    int a = tid >> 5, r = tid & 31;
    __shared__ float carry[32];
    if (tid < 32) carry[tid] = 0.f;
    __syncthreads();

    if (!bwd) {
        float pnext = phiN[(size_t)(0 * NB + n) * 1024 + r * 32 + a];
        for (int t = 0; t < TT - 1; ++t) {
            float cr = carry[r];
            float cold = (tid < 32) ? carry[tid] : 0.f;
            float p = pnext + cr;
            if (t + 1 < TT - 1)
                pnext = phiN[(size_t)((t + 1) * NB + n) * 1024 + r * 32 + a];
            float m = p;
#pragma unroll
            for (int off = 16; off; off >>= 1) m = fmaxf(m, __shfl_xor(m, off));
            float s = expf(p - m);
#pragma unroll
            for (int off = 16; off; off >>= 1) s += __shfl_xor(s, off);
            float nv = m + logf(s);
            if (tid < 32) alphas_pre[((size_t)t * NB + n) * SPW + tid] = cold;
            __syncthreads();
            if (r == 0) carry[a] = nv;
            __syncthreads();
        }
        if (tid < 32) {
            float x = carry[tid];
            float m = x;
#pragma unroll
            for (int off = 16; off; off >>= 1) m = fmaxf(m, __shfl_xor(m, off));
            float s = expf(x - m);
#pragma unroll
            for (int off = 16; off; off >>= 1) s += __shfl_xor(s, off);
            float lg = logf(s);
            if (tid == 0) logZ[n] = m + lg;
            out[2 + n * 32 + tid] = (x - m) - lg;
        }
    } else {
        float pnext = phiN[(size_t)((TT - 2) * NB + n) * 1024 + a * 32 + r];
        for (int t = TT - 2; t >= 0; --t) {
            float cr = carry[r];
            float cold = (tid < 32) ? carry[tid] : 0.f;
            float p = pnext + cr;
            if (t > 0)
                pnext = phiN[(size_t)((t - 1) * NB + n) * 1024 + a * 32 + r];
            float m = p;
#pragma unroll
            for (int off = 16; off; off >>= 1) m = fmaxf(m, __shfl_xor(m, off));
            float s = expf(p - m);
#pragma unroll
            for (int off = 16; off; off >>= 1) s += __shfl_xor(s, off);
            float nv = m + logf(s);
            if (tid < 32) betas_next[((size_t)t * NB + n) * SPW + tid] = cold;
            __syncthreads();
            if (r == 0) carry[a] = nv;
            __syncthreads();
        }
    }
}

// ---------------------------------------------------------------------------
// K16: elbo + fused finalize (last block writes out[0], out[1])
// ---------------------------------------------------------------------------
__global__ __launch_bounds__(256) void elbo_fin_kernel(
    const float* __restrict__ phiN, const float* __restrict__ alphas_pre,
    const float* __restrict__ betas_next, const float* __restrict__ logZ,
    double* __restrict__ elbo_acc, unsigned* __restrict__ done_cnt,
    float* __restrict__ out)
{
    int t = blockIdx.x / NB;
    int n = blockIdx.x - t * NB;
    int tid = threadIdx.x;
    __shared__ float ap[32], bn[32];
    if (tid < 32) ap[tid] = alphas_pre[((size_t)t * NB + n) * SPW + tid];
    else if (tid < 64) bn[tid - 32] = betas_next[((size_t)t * NB + n) * SPW + (tid - 32)];
    __syncthreads();
    float lz = logZ[n];
    size_t base = (size_t)(t * NB + n) * 1024;
    double local = 0.0;
#pragma unroll
    for (int e = tid; e < 1024; e += 256) {
        int i = e >> 5, j = e & 31;
        float ph = phiN[base + e];
        float lm = ap[i] + ph + bn[j] - lz;
        local += (double)(expf(lm) * ph);
    }
#pragma unroll
    for (int off = 32; off; off >>= 1) local += __shfl_down(local, off);
    __shared__ double wsum[4];
    if ((tid & 63) == 0) wsum[tid >> 6] = local;
    __syncthreads();
    if (tid == 0) {
        atomicAdd(elbo_acc, wsum[0] + wsum[1] + wsum[2] + wsum[3]);
        __threadfence();
        unsigned old = atomicAdd(done_cnt, 1u);
        if (old == (unsigned)(NTOK - 1)) {
            double e = atomicAdd(elbo_acc, 0.0);   // fresh device-scope load
            out[0] = (float)e;
            float s = 0.f;
            for (int k = 0; k < NB; ++k) s += logZ[k];
            out[1] = s;
        }
    }
}

// ---------------------------------------------------------------------------
extern "C" void kernel_launch(void* const* d_in, const int* in_sizes, int n_in,
                              void* d_out, int out_size, void* d_ws, size_t ws_size,
                              hipStream_t stream) {
    (void)in_sizes; (void)n_in; (void)out_size; (void)ws_size;
    const float* start_emb = (const float*)d_in[0];
    const float* sw1  = (const float*)d_in[1];
    const float* sb1  = (const float*)d_in[2];
    const float* sw2  = (const float*)d_in[3];
    const float* sb2  = (const float*)d_in[4];
    const float* sow  = (const float*)d_in[5];
    const float* state_emb = (const float*)d_in[7];
    const float* tw1  = (const float*)d_in[8];
    const float* tb1  = (const float*)d_in[9];
    const float* tw2  = (const float*)d_in[10];
    const float* tb2  = (const float*)d_in[11];
    const float* nsp  = (const float*)d_in[12];
    const float* pre_emb = (const float*)d_in[13];
    const float* ew1  = (const float*)d_in[14];
    const float* eb1  = (const float*)d_in[15];
    const float* ew2  = (const float*)d_in[16];
    const float* eb2  = (const float*)d_in[17];
    const float* eow  = (const float*)d_in[18];
    const float* eob  = (const float*)d_in[19];
    const int*   text = (const int*)d_in[20];
    const int*   w2s  = (const int*)d_in[21];

    float* ws = (float*)d_ws;
    float* TL      = ws + OFF_TL;
    float* s_tmp   = ws + OFF_STMP;
    float* startl  = ws + OFF_START;
    float* lse1    = ws + OFF_LSE1;
    unsigned* rmax = (unsigned*)(ws + OFF_RMAX);
    float* rsum    = ws + OFF_RSUM;
    float* den     = ws + OFF_DEN;
    float* logZ    = ws + OFF_LOGZ;
    unsigned* done = (unsigned*)(ws + OFF_LOGZ + 40);
    double* elboA  = (double*)(ws + OFF_ELBO);
    unsigned short* Xp  = (unsigned short*)(ws + OFF_XP);
    unsigned short* Hp  = (unsigned short*)(ws + OFF_HP);
    unsigned short* W1p = (unsigned short*)(ws + OFF_W1P);
    unsigned short* W2p = (unsigned short*)(ws + OFF_W2P);
    unsigned short* Ap  = (unsigned short*)(ws + OFF_AP);
    unsigned short* Bp  = (unsigned short*)(ws + OFF_BP);
    float* ewT     = ws + OFF_EWT;
    float* Lm      = ws + OFF_L;
    float* obs     = ws + OFF_OBS;
    float* phiN    = ws + OFF_PHI;
    float* res_e   = ws + OFF_RES_E;
    float* alph    = ws + OFF_ALPH;
    float* beta    = ws + OFF_BETA;
    int* cnt       = (int*)(ws + OFF_CNT);
    int* offs      = (int*)(ws + OFF_OFFS);
    int* cur       = (int*)(ws + OFF_CUR);
    int* ent       = (int*)(ws + OFF_ENT);
    float* out     = (float*)d_out;

    init_kernel<<<16, 256, 0, stream>>>(rmax, rsum, cnt, s_tmp, done, elboA);

    // pack inputs/weights; run the three residual MLPs on MFMA
    pack_all_kernel<<<4480, 256, 0, stream>>>(start_emb, state_emb, pre_emb, nsp,
                                              sw1, tw1, ew1, sw2, tw2, ew2,
                                              Xp, Bp, W1p, W2p);
    gemm_layer1<<<dim3(2, 96), 256, 0, stream>>>(Xp, W1p, sb1, tb1, eb1, Hp);
    gemm_layer2<<<dim3(2, 96), 256, 0, stream>>>(Hp, W2p, sb2, tb2, eb2,
                                                 start_emb, state_emb, pre_emb,
                                                 sow, s_tmp, Ap, res_e);
    logsoftmax_start_kernel<<<1, 1024, 0, stream>>>(s_tmp, startl);

    // transition path: TL GEMM + row lse
    gemm_bt_kernel<<<dim3(32, 32), 256, 0, stream>>>(Ap, Bp, TL);
    row_lse_kernel<<<C_, 256, 0, stream>>>(TL, lse1);

    // emission path (sparse: only the V*SPW masked entries)
    transpose_kernel<<<dim3(V_ / 32, H_ / 32), 256, 0, stream>>>(eow, ewT);
    em_logits_kernel<<<V_, 256, 0, stream>>>(res_e, ewT, eob, w2s, Lm);
    row_max_kernel<<<V_ / 8, 256, 0, stream>>>(w2s, Lm, rmax);
    row_sum_kernel<<<V_ / 8, 256, 0, stream>>>(w2s, Lm, rmax, rsum);
    denom_hist_kernel<<<16 + NITEM / 256, 256, 0, stream>>>(rmax, rsum, den, text, w2s, cnt);
    prefix_kernel<<<1, 1024, 0, stream>>>(cnt, offs, cur);
    obs_fill_kernel<<<512 + NITEM / 256, 256, 0, stream>>>(text, w2s, Lm, den, obs, cur, ent);

    // phi assembly + scans + outputs
    phi_gather_kernel<<<C_, 256, 0, stream>>>(TL, offs, ent, lse1, startl,
                                              obs, text, w2s, phiN);
    scan_kernel<<<2 * NB, 1024, 0, stream>>>(phiN, alph, beta, logZ, out);
    elbo_fin_kernel<<<NTOK, 256, 0, stream>>>(phiN, alph, beta, logZ, elboA, done, out);
}